// Round 1
// baseline (1143.318 us; speedup 1.0000x reference)
//
#include <hip/hip_runtime.h>

#define N_NODES 100000
#define N_EDGES 1000000
#define N_GRAPHS 2000
#define D 64

// ---------------- edge scatter-add: agg[dst] += feat[src] ----------------
__global__ __launch_bounds__(256) void scatter_kernel(
    const float* __restrict__ feat, const int* __restrict__ ei,
    float* __restrict__ agg, int nE)
{
  int gtid = blockIdx.x * blockDim.x + threadIdx.x;
  int wave = gtid >> 6;
  int lane = threadIdx.x & 63;
  int nw = (gridDim.x * blockDim.x) >> 6;
  for (int e = wave; e < nE; e += nw) {
    int s = ei[e];
    int d = ei[nE + e];
    float v = feat[(size_t)s * D + lane];
    unsafeAtomicAdd(&agg[(size_t)d * D + lane], v);
  }
}

// ---- conv layer: h = leaky(leaky(BN( ((1+eps)x + agg) @ W + b ))) ----
// BM=128, BN=64, BK=16, 256 threads, 8x4 micro-tile
__global__ __launch_bounds__(256) void conv_kernel(
    const float* __restrict__ xin, const float* __restrict__ agg,
    const float* __restrict__ W, const float* __restrict__ bias,
    const float* __restrict__ gamma, const float* __restrict__ beta,
    const float* __restrict__ mean, const float* __restrict__ var,
    const float* __restrict__ epsp, float* __restrict__ hout,
    float* __restrict__ hpool, const int* __restrict__ batch, int do_pool)
{
  __shared__ float As[16][128];
  __shared__ float Bs[16][64];
  int t = threadIdx.x;
  int bm0 = blockIdx.x * 128;
  float onepe = 1.0f + epsp[0];
  int ty = t >> 4, tx = t & 15;
  float acc[8][4];
#pragma unroll
  for (int i = 0; i < 8; ++i)
#pragma unroll
    for (int j = 0; j < 4; ++j) acc[i][j] = 0.f;

  for (int k0 = 0; k0 < D; k0 += 16) {
#pragma unroll
    for (int i = 0; i < 2; ++i) {
      int f = t + i * 256;
      int row = f >> 2, kq = (f & 3) << 2;
      int grow = bm0 + row;
      float4 av = make_float4(0.f, 0.f, 0.f, 0.f);
      if (grow < N_NODES) {
        const float4 xv = *(const float4*)(xin + (size_t)grow * D + k0 + kq);
        const float4 gv = *(const float4*)(agg + (size_t)grow * D + k0 + kq);
        av.x = onepe * xv.x + gv.x;
        av.y = onepe * xv.y + gv.y;
        av.z = onepe * xv.z + gv.z;
        av.w = onepe * xv.w + gv.w;
      }
      As[kq + 0][row] = av.x; As[kq + 1][row] = av.y;
      As[kq + 2][row] = av.z; As[kq + 3][row] = av.w;
    }
    {
      int row = t >> 4, c4 = t & 15;
      *(float4*)&Bs[row][c4 * 4] = *(const float4*)(W + (size_t)(k0 + row) * D + c4 * 4);
    }
    __syncthreads();
#pragma unroll
    for (int kk = 0; kk < 16; ++kk) {
      float4 a0 = *(const float4*)&As[kk][ty * 8];
      float4 a1 = *(const float4*)&As[kk][ty * 8 + 4];
      float4 b0 = *(const float4*)&Bs[kk][tx * 4];
      float a[8] = {a0.x, a0.y, a0.z, a0.w, a1.x, a1.y, a1.z, a1.w};
      float b[4] = {b0.x, b0.y, b0.z, b0.w};
#pragma unroll
      for (int i = 0; i < 8; ++i)
#pragma unroll
        for (int j = 0; j < 4; ++j) acc[i][j] = fmaf(a[i], b[j], acc[i][j]);
    }
    __syncthreads();
  }
  int colb = tx * 4;
  float sc[4], sh[4];
#pragma unroll
  for (int j = 0; j < 4; ++j) {
    int c = colb + j;
    float s = gamma[c] * rsqrtf(var[c] + 1e-5f);
    sc[j] = s;
    sh[j] = (bias[c] - mean[c]) * s + beta[c];
  }
#pragma unroll
  for (int i = 0; i < 8; ++i) {
    int grow = bm0 + ty * 8 + i;
    if (grow < N_NODES) {
      float vv[4];
#pragma unroll
      for (int j = 0; j < 4; ++j) {
        float z = acc[i][j] * sc[j] + sh[j];
        z = (z > 0.f) ? z : 0.01f * z;
        z = (z > 0.f) ? z : 0.01f * z;
        vv[j] = z;
      }
      *(float4*)(hout + (size_t)grow * D + colb) = make_float4(vv[0], vv[1], vv[2], vv[3]);
      if (do_pool) {
        int g = batch[grow];
#pragma unroll
        for (int j = 0; j < 4; ++j)
          unsafeAtomicAdd(&hpool[(size_t)g * D + colb + j], vv[j]);
      }
    }
  }
}

// ---- classifier GEMM: C = leaky(A @ B + bias), BM=BN=128, BK=16, 8x8 ----
// MODE 0: A is virtual hcat(h1,h2,h3,hpool[batch]) [N,256]
// MODE 1: A is a plain [N,256] buffer
template <int MODE>
__global__ __launch_bounds__(256) void clf_gemm_kernel(
    const float* __restrict__ A,
    const float* __restrict__ h1, const float* __restrict__ h2,
    const float* __restrict__ h3, const float* __restrict__ hpool,
    const int* __restrict__ batch,
    const float* __restrict__ B, const float* __restrict__ bias,
    float* __restrict__ Cout, int ldb)
{
  __shared__ float As[16][128];
  __shared__ float Bs[16][128];
  int t = threadIdx.x;
  int ty = t >> 4, tx = t & 15;
  int bm0 = blockIdx.x * 128;
  int bn0 = blockIdx.y * 128;
  float acc[8][8];
#pragma unroll
  for (int i = 0; i < 8; ++i)
#pragma unroll
    for (int j = 0; j < 8; ++j) acc[i][j] = 0.f;

  for (int k0 = 0; k0 < 256; k0 += 16) {
#pragma unroll
    for (int i = 0; i < 2; ++i) {
      int f = t + i * 256;
      int row = f >> 2, kq = (f & 3) << 2;
      int grow = bm0 + row;
      float4 av = make_float4(0.f, 0.f, 0.f, 0.f);
      if (grow < N_NODES) {
        int k = k0 + kq;
        if (MODE == 0) {
          if (k < 64)
            av = *(const float4*)(h1 + (size_t)grow * 64 + k);
          else if (k < 128)
            av = *(const float4*)(h2 + (size_t)grow * 64 + (k - 64));
          else if (k < 192)
            av = *(const float4*)(h3 + (size_t)grow * 64 + (k - 128));
          else
            av = *(const float4*)(hpool + (size_t)batch[grow] * 64 + (k - 192));
        } else {
          av = *(const float4*)(A + (size_t)grow * 256 + k);
        }
      }
      As[kq + 0][row] = av.x; As[kq + 1][row] = av.y;
      As[kq + 2][row] = av.z; As[kq + 3][row] = av.w;
    }
#pragma unroll
    for (int i = 0; i < 2; ++i) {
      int f = t + i * 256;
      int row = f >> 5, c4 = f & 31;
      *(float4*)&Bs[row][c4 * 4] = *(const float4*)(B + (size_t)(k0 + row) * ldb + bn0 + c4 * 4);
    }
    __syncthreads();
#pragma unroll
    for (int kk = 0; kk < 16; ++kk) {
      float4 a0 = *(const float4*)&As[kk][ty * 8];
      float4 a1 = *(const float4*)&As[kk][ty * 8 + 4];
      float4 b0 = *(const float4*)&Bs[kk][tx * 8];
      float4 b1 = *(const float4*)&Bs[kk][tx * 8 + 4];
      float a[8] = {a0.x, a0.y, a0.z, a0.w, a1.x, a1.y, a1.z, a1.w};
      float b[8] = {b0.x, b0.y, b0.z, b0.w, b1.x, b1.y, b1.z, b1.w};
#pragma unroll
      for (int i = 0; i < 8; ++i)
#pragma unroll
        for (int j = 0; j < 8; ++j) acc[i][j] = fmaf(a[i], b[j], acc[i][j]);
    }
    __syncthreads();
  }
#pragma unroll
  for (int i = 0; i < 8; ++i) {
    int grow = bm0 + ty * 8 + i;
    if (grow < N_NODES) {
#pragma unroll
      for (int jq = 0; jq < 2; ++jq) {
        float ov[4];
#pragma unroll
        for (int j = 0; j < 4; ++j) {
          int c = bn0 + tx * 8 + jq * 4 + j;
          float z = acc[i][jq * 4 + j] + bias[c];
          ov[j] = (z > 0.f) ? z : 0.01f * z;
        }
        *(float4*)(Cout + (size_t)grow * ldb + bn0 + tx * 8 + jq * 4) =
            make_float4(ov[0], ov[1], ov[2], ov[3]);
      }
    }
  }
}

// ---- final: out = sigmoid(hb . Wf + fb), one wave per node ----
__global__ __launch_bounds__(256) void final_kernel(
    const float* __restrict__ hb, const float* __restrict__ Wf,
    const float* __restrict__ fbias, float* __restrict__ out, int n)
{
  int gtid = blockIdx.x * blockDim.x + threadIdx.x;
  int wave = gtid >> 6;
  int lane = threadIdx.x & 63;
  int nw = (gridDim.x * blockDim.x) >> 6;
  float w0 = Wf[lane], w1 = Wf[64 + lane];
  float fb = fbias[0];
  for (int v = wave; v < n; v += nw) {
    float s = hb[(size_t)v * 128 + lane] * w0 + hb[(size_t)v * 128 + 64 + lane] * w1;
#pragma unroll
    for (int m = 32; m; m >>= 1) s += __shfl_xor(s, m, 64);
    if (lane == 0) {
      float z = s + fb;
      out[v] = 1.0f / (1.0f + expf(-z));
    }
  }
}

extern "C" void kernel_launch(void* const* d_in, const int* in_sizes, int n_in,
                              void* d_out, int out_size, void* d_ws, size_t ws_size,
                              hipStream_t stream)
{
  const float* x     = (const float*)d_in[0];
  const int*   ei    = (const int*)d_in[1];
  const int*   batch = (const int*)d_in[2];
  const float* convW = (const float*)d_in[3];
  const float* convb = (const float*)d_in[4];
  const float* gam   = (const float*)d_in[5];
  const float* bet   = (const float*)d_in[6];
  const float* mean  = (const float*)d_in[7];
  const float* var   = (const float*)d_in[8];
  const float* eps   = (const float*)d_in[9];
  const float* W0    = (const float*)d_in[10];
  const float* b0    = (const float*)d_in[11];
  const float* W1    = (const float*)d_in[12];
  const float* b1    = (const float*)d_in[13];
  const float* Wf    = (const float*)d_in[14];
  const float* fb    = (const float*)d_in[15];
  float* out = (float*)d_out;

  // workspace layout (floats), with liveness overlays:
  //  h1: 0          .. 6.4e6      (live conv1 -> gemm0)
  //  h2: 6.4e6      .. 12.8e6     (live conv2 -> gemm0)
  //  h3: 12.8e6     .. 19.2e6     (live conv3 -> gemm0)
  //  hpool: 19.2e6  .. 19.328e6   (live conv3 -> gemm0)
  //  agg: 19.328e6  .. 25.728e6   (live scatter_l -> conv_l; dead before gemm0)
  //  ha : 19.328e6  .. 44.928e6   (gemm0 -> gemm1) overlays agg
  //  hb : 0         .. 12.8e6     (gemm1 -> final) overlays h1,h2
  float* ws = (float*)d_ws;
  float* h1    = ws;
  float* h2    = ws + 6400000;
  float* h3    = ws + 12800000;
  float* hpool = ws + 19200000;
  float* agg   = ws + 19328000;
  float* ha    = ws + 19328000;
  float* hb    = ws;

  dim3 b256(256);
  int gridX = (N_NODES + 127) / 128;

  const float* lin[3] = {x, h1, h2};
  float* lout[3] = {h1, h2, h3};

  hipMemsetAsync(hpool, 0, (size_t)N_GRAPHS * D * sizeof(float), stream);
  for (int l = 0; l < 3; ++l) {
    hipMemsetAsync(agg, 0, (size_t)N_NODES * D * sizeof(float), stream);
    scatter_kernel<<<8192, b256, 0, stream>>>(lin[l], ei, agg, N_EDGES);
    conv_kernel<<<gridX, b256, 0, stream>>>(
        lin[l], agg, convW + (size_t)l * D * D, convb + (size_t)l * D,
        gam + (size_t)l * D, bet + (size_t)l * D, mean + (size_t)l * D,
        var + (size_t)l * D, eps + l, lout[l], hpool, batch, (l == 2) ? 1 : 0);
  }
  clf_gemm_kernel<0><<<dim3(gridX, 2), b256, 0, stream>>>(
      nullptr, h1, h2, h3, hpool, batch, W0, b0, ha, 256);
  clf_gemm_kernel<1><<<dim3(gridX, 1), b256, 0, stream>>>(
      ha, nullptr, nullptr, nullptr, nullptr, nullptr, W1, b1, hb, 128);
  final_kernel<<<4096, b256, 0, stream>>>(hb, Wf, fb, out, N_NODES);
}

// Round 2
// 883.658 us; speedup vs baseline: 1.2938x; 1.2938x over previous
//
#include <hip/hip_runtime.h>

#define N_NODES 100000
#define N_EDGES 1000000
#define N_GRAPHS 2000
#define D 64

// ===================== CSR build (once, reused for 3 layers) =====================
__global__ __launch_bounds__(256) void deg_hist_kernel(
    const int* __restrict__ ei, int* __restrict__ deg)
{
  int i = blockIdx.x * blockDim.x + threadIdx.x;
  if (i < N_EDGES) atomicAdd(&deg[ei[N_EDGES + i]], 1);
}

// per-block (2048 items) inclusive scan + block sums
__global__ __launch_bounds__(256) void scan1_kernel(
    const int* __restrict__ deg, int* __restrict__ incl, int* __restrict__ bsum)
{
  __shared__ int sh[256];
  int t = threadIdx.x;
  int base = blockIdx.x * 2048 + t * 8;
  int v[8];
  int run = 0;
#pragma unroll
  for (int j = 0; j < 8; ++j) {
    int idx = base + j;
    int xv = (idx < N_NODES) ? deg[idx] : 0;
    run += xv;
    v[j] = run;
  }
  sh[t] = run;
  __syncthreads();
  for (int off = 1; off < 256; off <<= 1) {
    int a = (t >= off) ? sh[t - off] : 0;
    __syncthreads();
    sh[t] += a;
    __syncthreads();
  }
  int prev = (t > 0) ? sh[t - 1] : 0;
#pragma unroll
  for (int j = 0; j < 8; ++j) {
    int idx = base + j;
    if (idx < N_NODES) incl[idx] = v[j] + prev;
  }
  if (t == 255) bsum[blockIdx.x] = sh[255];
}

__global__ void scan2_kernel(int* __restrict__ bsum, int nb)
{
  if (blockIdx.x == 0 && threadIdx.x == 0) {
    int run = 0;
    for (int i = 0; i < nb; ++i) { int xv = bsum[i]; bsum[i] = run; run += xv; }
  }
}

__global__ __launch_bounds__(256) void scan3_kernel(
    const int* __restrict__ incl, const int* __restrict__ bsum,
    const int* __restrict__ deg, int* __restrict__ row_ptr, int* __restrict__ cursor)
{
  int i = blockIdx.x * blockDim.x + threadIdx.x;
  if (i < N_NODES) {
    int val = incl[i] + bsum[i >> 11];
    row_ptr[i + 1] = val;
    cursor[i] = val - deg[i];
    if (i == 0) row_ptr[0] = 0;
  }
}

__global__ __launch_bounds__(256) void fill_csr_kernel(
    const int* __restrict__ ei, int* __restrict__ cursor, int* __restrict__ srcs)
{
  int i = blockIdx.x * blockDim.x + threadIdx.x;
  if (i < N_EDGES) {
    int s = ei[i];
    int d = ei[N_EDGES + i];
    int pos = atomicAdd(&cursor[d], 1);
    srcs[pos] = s;
  }
}

// ---------------- CSR gather aggregation: agg[v] = sum_{j in N(v)} feat[j] ----------------
__global__ __launch_bounds__(256) void csr_agg_kernel(
    const float* __restrict__ feat, const int* __restrict__ row_ptr,
    const int* __restrict__ srcs, float* __restrict__ agg)
{
  int wid = (blockIdx.x * blockDim.x + threadIdx.x) >> 6;
  int lane = threadIdx.x & 63;
  if (wid >= N_NODES) return;
  int beg = row_ptr[wid];
  int end = row_ptr[wid + 1];
  float s = 0.f;
  for (int e = beg; e < end; ++e)
    s += feat[(size_t)srcs[e] * D + lane];
  agg[(size_t)wid * D + lane] = s;
}

// ---- conv layer: h = leaky(leaky(BN( ((1+eps)x + agg) @ W + b ))) ----
// BM=128, BN=64, BK=16, 256 threads, 8x4 micro-tile
__global__ __launch_bounds__(256) void conv_kernel(
    const float* __restrict__ xin, const float* __restrict__ agg,
    const float* __restrict__ W, const float* __restrict__ bias,
    const float* __restrict__ gamma, const float* __restrict__ beta,
    const float* __restrict__ mean, const float* __restrict__ var,
    const float* __restrict__ epsp, float* __restrict__ hout,
    float* __restrict__ hpool, const int* __restrict__ batch, int do_pool)
{
  __shared__ float As[16][132];
  __shared__ float Bs[16][64];
  int t = threadIdx.x;
  int bm0 = blockIdx.x * 128;
  float onepe = 1.0f + epsp[0];
  int ty = t >> 4, tx = t & 15;
  float acc[8][4];
#pragma unroll
  for (int i = 0; i < 8; ++i)
#pragma unroll
    for (int j = 0; j < 4; ++j) acc[i][j] = 0.f;

  for (int k0 = 0; k0 < D; k0 += 16) {
#pragma unroll
    for (int i = 0; i < 2; ++i) {
      int f = t + i * 256;
      int row = f >> 2, kq = (f & 3) << 2;
      int grow = bm0 + row;
      float4 av = make_float4(0.f, 0.f, 0.f, 0.f);
      if (grow < N_NODES) {
        const float4 xv = *(const float4*)(xin + (size_t)grow * D + k0 + kq);
        const float4 gv = *(const float4*)(agg + (size_t)grow * D + k0 + kq);
        av.x = onepe * xv.x + gv.x;
        av.y = onepe * xv.y + gv.y;
        av.z = onepe * xv.z + gv.z;
        av.w = onepe * xv.w + gv.w;
      }
      As[kq + 0][row] = av.x; As[kq + 1][row] = av.y;
      As[kq + 2][row] = av.z; As[kq + 3][row] = av.w;
    }
    {
      int row = t >> 4, c4 = t & 15;
      *(float4*)&Bs[row][c4 * 4] = *(const float4*)(W + (size_t)(k0 + row) * D + c4 * 4);
    }
    __syncthreads();
#pragma unroll
    for (int kk = 0; kk < 16; ++kk) {
      float4 a0 = *(const float4*)&As[kk][ty * 8];
      float4 a1 = *(const float4*)&As[kk][ty * 8 + 4];
      float4 b0 = *(const float4*)&Bs[kk][tx * 4];
      float a[8] = {a0.x, a0.y, a0.z, a0.w, a1.x, a1.y, a1.z, a1.w};
      float b[4] = {b0.x, b0.y, b0.z, b0.w};
#pragma unroll
      for (int i = 0; i < 8; ++i)
#pragma unroll
        for (int j = 0; j < 4; ++j) acc[i][j] = fmaf(a[i], b[j], acc[i][j]);
    }
    __syncthreads();
  }
  int colb = tx * 4;
  float sc[4], sh[4];
#pragma unroll
  for (int j = 0; j < 4; ++j) {
    int c = colb + j;
    float s = gamma[c] * rsqrtf(var[c] + 1e-5f);
    sc[j] = s;
    sh[j] = (bias[c] - mean[c]) * s + beta[c];
  }
#pragma unroll
  for (int i = 0; i < 8; ++i) {
    int grow = bm0 + ty * 8 + i;
    if (grow < N_NODES) {
      float vv[4];
#pragma unroll
      for (int j = 0; j < 4; ++j) {
        float z = acc[i][j] * sc[j] + sh[j];
        z = (z > 0.f) ? z : 0.01f * z;
        z = (z > 0.f) ? z : 0.01f * z;
        vv[j] = z;
      }
      *(float4*)(hout + (size_t)grow * D + colb) = make_float4(vv[0], vv[1], vv[2], vv[3]);
      if (do_pool) {
        int g = batch[grow];
#pragma unroll
        for (int j = 0; j < 4; ++j)
          unsafeAtomicAdd(&hpool[(size_t)g * D + colb + j], vv[j]);
      }
    }
  }
}

// ---- GEMM0: ha = leaky(hcat(h1,h2,h3,hpool[batch]) @ W0 + b0) ----
// BM=BN=128, BK=16, 8x8 micro-tile, cols {tx*4+j, 64+tx*4+j}
__global__ __launch_bounds__(256) void clf_gemm0_kernel(
    const float* __restrict__ h1, const float* __restrict__ h2,
    const float* __restrict__ h3, const float* __restrict__ hpool,
    const int* __restrict__ batch,
    const float* __restrict__ B, const float* __restrict__ bias,
    float* __restrict__ Cout)
{
  __shared__ float As[16][132];
  __shared__ float Bs[16][132];
  int t = threadIdx.x;
  int ty = t >> 4, tx = t & 15;
  int bm0 = blockIdx.x * 128;
  int bn0 = blockIdx.y * 128;
  float acc[8][8];
#pragma unroll
  for (int i = 0; i < 8; ++i)
#pragma unroll
    for (int j = 0; j < 8; ++j) acc[i][j] = 0.f;

  for (int k0 = 0; k0 < 256; k0 += 16) {
#pragma unroll
    for (int i = 0; i < 2; ++i) {
      int f = t + i * 256;
      int row = f >> 2, kq = (f & 3) << 2;
      int grow = bm0 + row;
      float4 av = make_float4(0.f, 0.f, 0.f, 0.f);
      if (grow < N_NODES) {
        int k = k0 + kq;
        if (k < 64)
          av = *(const float4*)(h1 + (size_t)grow * 64 + k);
        else if (k < 128)
          av = *(const float4*)(h2 + (size_t)grow * 64 + (k - 64));
        else if (k < 192)
          av = *(const float4*)(h3 + (size_t)grow * 64 + (k - 128));
        else
          av = *(const float4*)(hpool + (size_t)batch[grow] * 64 + (k - 192));
      }
      As[kq + 0][row] = av.x; As[kq + 1][row] = av.y;
      As[kq + 2][row] = av.z; As[kq + 3][row] = av.w;
    }
#pragma unroll
    for (int i = 0; i < 2; ++i) {
      int f = t + i * 256;
      int row = f >> 5, c4 = f & 31;
      *(float4*)&Bs[row][c4 * 4] = *(const float4*)(B + (size_t)(k0 + row) * 256 + bn0 + c4 * 4);
    }
    __syncthreads();
#pragma unroll
    for (int kk = 0; kk < 16; ++kk) {
      float4 a0 = *(const float4*)&As[kk][ty * 8];
      float4 a1 = *(const float4*)&As[kk][ty * 8 + 4];
      float4 b0 = *(const float4*)&Bs[kk][tx * 4];
      float4 b1 = *(const float4*)&Bs[kk][64 + tx * 4];
      float a[8] = {a0.x, a0.y, a0.z, a0.w, a1.x, a1.y, a1.z, a1.w};
      float b[8] = {b0.x, b0.y, b0.z, b0.w, b1.x, b1.y, b1.z, b1.w};
#pragma unroll
      for (int i = 0; i < 8; ++i)
#pragma unroll
        for (int j = 0; j < 8; ++j) acc[i][j] = fmaf(a[i], b[j], acc[i][j]);
    }
    __syncthreads();
  }
#pragma unroll
  for (int i = 0; i < 8; ++i) {
    int grow = bm0 + ty * 8 + i;
    if (grow < N_NODES) {
      float ov[4];
#pragma unroll
      for (int j = 0; j < 4; ++j) {
        float z = acc[i][j] + bias[bn0 + tx * 4 + j];
        ov[j] = (z > 0.f) ? z : 0.01f * z;
      }
      *(float4*)(Cout + (size_t)grow * 256 + bn0 + tx * 4) =
          make_float4(ov[0], ov[1], ov[2], ov[3]);
#pragma unroll
      for (int j = 0; j < 4; ++j) {
        float z = acc[i][4 + j] + bias[bn0 + 64 + tx * 4 + j];
        ov[j] = (z > 0.f) ? z : 0.01f * z;
      }
      *(float4*)(Cout + (size_t)grow * 256 + bn0 + 64 + tx * 4) =
          make_float4(ov[0], ov[1], ov[2], ov[3]);
    }
  }
}

// ---- GEMM1 fused with final layer + sigmoid ----
// h2row = leaky(ha_row @ W1 + b1);  out = sigmoid(h2row . Wf + fb)
__global__ __launch_bounds__(256) void gemm1_final_kernel(
    const float* __restrict__ A, const float* __restrict__ B,
    const float* __restrict__ bias, const float* __restrict__ Wf,
    const float* __restrict__ fbias, float* __restrict__ out)
{
  __shared__ float As[16][132];
  __shared__ float Bs[16][132];
  int t = threadIdx.x;
  int ty = t >> 4, tx = t & 15;
  int bm0 = blockIdx.x * 128;
  float acc[8][8];
#pragma unroll
  for (int i = 0; i < 8; ++i)
#pragma unroll
    for (int j = 0; j < 8; ++j) acc[i][j] = 0.f;

  for (int k0 = 0; k0 < 256; k0 += 16) {
#pragma unroll
    for (int i = 0; i < 2; ++i) {
      int f = t + i * 256;
      int row = f >> 2, kq = (f & 3) << 2;
      int grow = bm0 + row;
      float4 av = make_float4(0.f, 0.f, 0.f, 0.f);
      if (grow < N_NODES)
        av = *(const float4*)(A + (size_t)grow * 256 + k0 + kq);
      As[kq + 0][row] = av.x; As[kq + 1][row] = av.y;
      As[kq + 2][row] = av.z; As[kq + 3][row] = av.w;
    }
    {
      // 16 rows x 32 float4 = 512 slots, 256 threads -> 2 each
#pragma unroll
      for (int i = 0; i < 2; ++i) {
        int f = t + i * 256;
        int row = f >> 5, c4 = f & 31;
        *(float4*)&Bs[row][c4 * 4] = *(const float4*)(B + (size_t)(k0 + row) * 128 + c4 * 4);
      }
    }
    __syncthreads();
#pragma unroll
    for (int kk = 0; kk < 16; ++kk) {
      float4 a0 = *(const float4*)&As[kk][ty * 8];
      float4 a1 = *(const float4*)&As[kk][ty * 8 + 4];
      float4 b0 = *(const float4*)&Bs[kk][tx * 4];
      float4 b1 = *(const float4*)&Bs[kk][64 + tx * 4];
      float a[8] = {a0.x, a0.y, a0.z, a0.w, a1.x, a1.y, a1.z, a1.w};
      float b[8] = {b0.x, b0.y, b0.z, b0.w, b1.x, b1.y, b1.z, b1.w};
#pragma unroll
      for (int i = 0; i < 8; ++i)
#pragma unroll
        for (int j = 0; j < 8; ++j) acc[i][j] = fmaf(a[i], b[j], acc[i][j]);
    }
    __syncthreads();
  }
  float fb = fbias[0];
#pragma unroll
  for (int i = 0; i < 8; ++i) {
    int grow = bm0 + ty * 8 + i;
    float s = 0.f;
#pragma unroll
    for (int j = 0; j < 4; ++j) {
      int c = tx * 4 + j;
      float z = acc[i][j] + bias[c];
      z = (z > 0.f) ? z : 0.01f * z;
      s += z * Wf[c];
      int c2 = 64 + tx * 4 + j;
      float z2 = acc[i][4 + j] + bias[c2];
      z2 = (z2 > 0.f) ? z2 : 0.01f * z2;
      s += z2 * Wf[c2];
    }
#pragma unroll
    for (int m = 1; m < 16; m <<= 1) s += __shfl_xor(s, m, 64);
    if (tx == 0 && grow < N_NODES)
      out[grow] = 1.0f / (1.0f + expf(-(s + fb)));
  }
}

extern "C" void kernel_launch(void* const* d_in, const int* in_sizes, int n_in,
                              void* d_out, int out_size, void* d_ws, size_t ws_size,
                              hipStream_t stream)
{
  const float* x     = (const float*)d_in[0];
  const int*   ei    = (const int*)d_in[1];
  const int*   batch = (const int*)d_in[2];
  const float* convW = (const float*)d_in[3];
  const float* convb = (const float*)d_in[4];
  const float* gam   = (const float*)d_in[5];
  const float* bet   = (const float*)d_in[6];
  const float* mean  = (const float*)d_in[7];
  const float* var   = (const float*)d_in[8];
  const float* eps   = (const float*)d_in[9];
  const float* W0    = (const float*)d_in[10];
  const float* b0    = (const float*)d_in[11];
  const float* W1    = (const float*)d_in[12];
  const float* b1    = (const float*)d_in[13];
  const float* Wf    = (const float*)d_in[14];
  const float* fb    = (const float*)d_in[15];
  float* out = (float*)d_out;

  // workspace layout (float offsets), with liveness overlays:
  //  h1    : 0          (6.4e6)   live conv1 -> gemm0
  //  h2    : 6,400,000  (6.4e6)   live conv2 -> gemm0
  //  h3    : 12,800,000 (6.4e6)   live conv3 -> gemm0
  //  hpool : 19,200,000 (128,000) live conv3 -> gemm0
  //  agg   : 19,328,000 (6.4e6)   live csr_agg_l -> conv_l
  //  CSR   : 25,728,000 .. ~27.2e6 (deg/incl/row_ptr/cursor/srcs/bsum), dead after conv3
  //  ha    : 19,328,000 (25.6e6)  gemm0 -> gemm1 (overlays agg+CSR) -> ends 44,928,000
  float* ws = (float*)d_ws;
  float* h1    = ws;
  float* h2    = ws + 6400000;
  float* h3    = ws + 12800000;
  float* hpool = ws + 19200000;
  float* agg   = ws + 19328000;
  int* deg     = (int*)(ws + 25728000);
  int* incl    = (int*)(ws + 25830000);
  int* row_ptr = (int*)(ws + 25932000);
  int* cursor  = (int*)(ws + 26040000);
  int* srcs    = (int*)(ws + 26140000);
  int* bsum    = (int*)(ws + 27150000);
  float* ha    = ws + 19328000;

  dim3 b256(256);
  int gridX = (N_NODES + 127) / 128;

  // ---- CSR build (once) ----
  hipMemsetAsync(deg, 0, (size_t)N_NODES * sizeof(int), stream);
  deg_hist_kernel<<<(N_EDGES + 255) / 256, b256, 0, stream>>>(ei, deg);
  scan1_kernel<<<(N_NODES + 2047) / 2048, b256, 0, stream>>>(deg, incl, bsum);
  scan2_kernel<<<1, 64, 0, stream>>>(bsum, (N_NODES + 2047) / 2048);
  scan3_kernel<<<(N_NODES + 255) / 256, b256, 0, stream>>>(incl, bsum, deg, row_ptr, cursor);
  fill_csr_kernel<<<(N_EDGES + 255) / 256, b256, 0, stream>>>(ei, cursor, srcs);

  hipMemsetAsync(hpool, 0, (size_t)N_GRAPHS * D * sizeof(float), stream);

  const float* lin[3] = {x, h1, h2};
  float* lout[3] = {h1, h2, h3};
  for (int l = 0; l < 3; ++l) {
    csr_agg_kernel<<<(N_NODES * 64 + 255) / 256, b256, 0, stream>>>(lin[l], row_ptr, srcs, agg);
    conv_kernel<<<gridX, b256, 0, stream>>>(
        lin[l], agg, convW + (size_t)l * D * D, convb + (size_t)l * D,
        gam + (size_t)l * D, bet + (size_t)l * D, mean + (size_t)l * D,
        var + (size_t)l * D, eps + l, lout[l], hpool, batch, (l == 2) ? 1 : 0);
  }
  clf_gemm0_kernel<<<dim3(gridX, 2), b256, 0, stream>>>(h1, h2, h3, hpool, batch, W0, b0, ha);
  gemm1_final_kernel<<<gridX, b256, 0, stream>>>(ha, W1, b1, Wf, fb, out);
}

// Round 4
// 822.771 us; speedup vs baseline: 1.3896x; 1.0740x over previous
//
#include <hip/hip_runtime.h>

#define N_NODES 100000
#define PADM    100096   // 782 * 128
#define HALFM   50048    // 391 * 128
#define N_EDGES 1000000
#define N_GRAPHS 2000
#define D 64

typedef __bf16    bf16x8 __attribute__((ext_vector_type(8)));
typedef __bf16    bf16x4 __attribute__((ext_vector_type(4)));
typedef float     f32x4  __attribute__((ext_vector_type(4)));

// ===================== CSR build (once, reused for 3 layers) =====================
__global__ __launch_bounds__(256) void deg_hist_kernel(
    const int* __restrict__ ei, int* __restrict__ deg)
{
  int i = blockIdx.x * blockDim.x + threadIdx.x;
  if (i < N_EDGES) atomicAdd(&deg[ei[N_EDGES + i]], 1);
}

__global__ __launch_bounds__(256) void scan1_kernel(
    const int* __restrict__ deg, int* __restrict__ incl, int* __restrict__ bsum)
{
  __shared__ int sh[256];
  int t = threadIdx.x;
  int base = blockIdx.x * 2048 + t * 8;
  int v[8];
  int run = 0;
#pragma unroll
  for (int j = 0; j < 8; ++j) {
    int idx = base + j;
    int xv = (idx < N_NODES) ? deg[idx] : 0;
    run += xv;
    v[j] = run;
  }
  sh[t] = run;
  __syncthreads();
  for (int off = 1; off < 256; off <<= 1) {
    int a = (t >= off) ? sh[t - off] : 0;
    __syncthreads();
    sh[t] += a;
    __syncthreads();
  }
  int prev = (t > 0) ? sh[t - 1] : 0;
#pragma unroll
  for (int j = 0; j < 8; ++j) {
    int idx = base + j;
    if (idx < N_NODES) incl[idx] = v[j] + prev;
  }
  if (t == 255) bsum[blockIdx.x] = sh[255];
}

__global__ void scan2_kernel(int* __restrict__ bsum, int nb)
{
  if (blockIdx.x == 0 && threadIdx.x == 0) {
    int run = 0;
    for (int i = 0; i < nb; ++i) { int xv = bsum[i]; bsum[i] = run; run += xv; }
  }
}

__global__ __launch_bounds__(256) void scan3_kernel(
    const int* __restrict__ incl, const int* __restrict__ bsum,
    const int* __restrict__ deg, int* __restrict__ row_ptr, int* __restrict__ cursor)
{
  int i = blockIdx.x * blockDim.x + threadIdx.x;
  if (i < N_NODES) {
    int val = incl[i] + bsum[i >> 11];
    row_ptr[i + 1] = val;
    cursor[i] = val - deg[i];
    if (i == 0) row_ptr[0] = 0;
  }
}

__global__ __launch_bounds__(256) void fill_csr_kernel(
    const int* __restrict__ ei, int* __restrict__ cursor, int* __restrict__ srcs)
{
  int i = blockIdx.x * blockDim.x + threadIdx.x;
  if (i < N_EDGES) {
    int s = ei[i];
    int d = ei[N_EDGES + i];
    int pos = atomicAdd(&cursor[d], 1);
    srcs[pos] = s;
  }
}

// --------- CSR gather aggregation: agg[v] = sum_{j in N(v)} feat[j] ---------
template <int INMODE>
__global__ __launch_bounds__(256) void csr_agg_kernel(
    const float* __restrict__ featf,
    const __bf16* __restrict__ fhi, const __bf16* __restrict__ flo, int c0,
    const int* __restrict__ row_ptr, const int* __restrict__ srcs,
    float* __restrict__ agg)
{
  int wid = (blockIdx.x * blockDim.x + threadIdx.x) >> 6;
  int lane = threadIdx.x & 63;
  if (wid >= N_NODES) return;
  int beg = row_ptr[wid];
  int end = row_ptr[wid + 1];
  float s = 0.f;
  for (int e = beg; e < end; ++e) {
    int src = srcs[e];
    if (INMODE == 0) {
      s += featf[(size_t)src * D + lane];
    } else {
      size_t o = (size_t)src * 256 + c0 + lane;
      s += (float)fhi[o] + (float)flo[o];
    }
  }
  agg[(size_t)wid * D + lane] = s;
}

// ---- conv layer: h = leaky(leaky(BN( ((1+eps)x + agg) @ W + b ))) ----
template <int INMODE, int POOL>
__global__ __launch_bounds__(256) void conv_kernel(
    const float* __restrict__ xf,
    const __bf16* __restrict__ xhi, const __bf16* __restrict__ xlo, int xc0,
    const float* __restrict__ agg,
    const float* __restrict__ W, const float* __restrict__ bias,
    const float* __restrict__ gamma, const float* __restrict__ beta,
    const float* __restrict__ mean, const float* __restrict__ var,
    const float* __restrict__ epsp,
    __bf16* __restrict__ ohi, __bf16* __restrict__ olo, int oc0,
    float* __restrict__ hpool, const int* __restrict__ batch)
{
  __shared__ float As[16][132];
  __shared__ float Bs[16][64];
  int t = threadIdx.x;
  int bm0 = blockIdx.x * 128;
  float onepe = 1.0f + epsp[0];
  int ty = t >> 4, tx = t & 15;
  float acc[8][4];
#pragma unroll
  for (int i = 0; i < 8; ++i)
#pragma unroll
    for (int j = 0; j < 4; ++j) acc[i][j] = 0.f;

  for (int k0 = 0; k0 < D; k0 += 16) {
#pragma unroll
    for (int i = 0; i < 2; ++i) {
      int f = t + i * 256;
      int row = f >> 2, kq = (f & 3) << 2;
      int grow = bm0 + row;
      float4 av = make_float4(0.f, 0.f, 0.f, 0.f);
      if (grow < N_NODES) {
        float4 xv;
        if (INMODE == 0) {
          xv = *(const float4*)(xf + (size_t)grow * D + k0 + kq);
        } else {
          bf16x4 h4 = *(const bf16x4*)(xhi + (size_t)grow * 256 + xc0 + k0 + kq);
          bf16x4 l4 = *(const bf16x4*)(xlo + (size_t)grow * 256 + xc0 + k0 + kq);
          xv.x = (float)h4[0] + (float)l4[0];
          xv.y = (float)h4[1] + (float)l4[1];
          xv.z = (float)h4[2] + (float)l4[2];
          xv.w = (float)h4[3] + (float)l4[3];
        }
        const float4 gv = *(const float4*)(agg + (size_t)grow * D + k0 + kq);
        av.x = onepe * xv.x + gv.x;
        av.y = onepe * xv.y + gv.y;
        av.z = onepe * xv.z + gv.z;
        av.w = onepe * xv.w + gv.w;
      }
      As[kq + 0][row] = av.x; As[kq + 1][row] = av.y;
      As[kq + 2][row] = av.z; As[kq + 3][row] = av.w;
    }
    {
      int row = t >> 4, c4 = t & 15;
      *(float4*)&Bs[row][c4 * 4] = *(const float4*)(W + (size_t)(k0 + row) * D + c4 * 4);
    }
    __syncthreads();
#pragma unroll
    for (int kk = 0; kk < 16; ++kk) {
      float4 a0 = *(const float4*)&As[kk][ty * 8];
      float4 a1 = *(const float4*)&As[kk][ty * 8 + 4];
      float4 b0 = *(const float4*)&Bs[kk][tx * 4];
      float a[8] = {a0.x, a0.y, a0.z, a0.w, a1.x, a1.y, a1.z, a1.w};
      float b[4] = {b0.x, b0.y, b0.z, b0.w};
#pragma unroll
      for (int i = 0; i < 8; ++i)
#pragma unroll
        for (int j = 0; j < 4; ++j) acc[i][j] = fmaf(a[i], b[j], acc[i][j]);
    }
    __syncthreads();
  }
  int colb = tx * 4;
  float sc[4], sh[4];
#pragma unroll
  for (int j = 0; j < 4; ++j) {
    int c = colb + j;
    float s = gamma[c] * rsqrtf(var[c] + 1e-5f);
    sc[j] = s;
    sh[j] = (bias[c] - mean[c]) * s + beta[c];
  }
#pragma unroll
  for (int i = 0; i < 8; ++i) {
    int grow = bm0 + ty * 8 + i;
    if (grow < N_NODES) {
      float vv[4];
      bf16x4 vh, vl;
#pragma unroll
      for (int j = 0; j < 4; ++j) {
        float z = acc[i][j] * sc[j] + sh[j];
        z = (z > 0.f) ? z : 0.01f * z;
        z = (z > 0.f) ? z : 0.01f * z;
        vv[j] = z;
        __bf16 h = (__bf16)z;
        vh[j] = h;
        vl[j] = (__bf16)(z - (float)h);
      }
      *(bf16x4*)(ohi + (size_t)grow * 256 + oc0 + colb) = vh;
      *(bf16x4*)(olo + (size_t)grow * 256 + oc0 + colb) = vl;
      if (POOL) {
        int g = batch[grow];
#pragma unroll
        for (int j = 0; j < 4; ++j)
          unsafeAtomicAdd(&hpool[(size_t)g * D + colb + j], vv[j]);
      }
    }
  }
}

// ---- pool rows -> concat cols 192..255 (hi/lo bf16) ----
__global__ __launch_bounds__(256) void pool_expand_kernel(
    const float* __restrict__ hpool, const int* __restrict__ batch,
    __bf16* __restrict__ ohi, __bf16* __restrict__ olo)
{
  int idx = blockIdx.x * blockDim.x + threadIdx.x;
  int v = idx >> 4, c4 = (idx & 15) << 2;
  if (v >= N_NODES) return;
  int g = batch[v];
  float4 pv = *(const float4*)(hpool + (size_t)g * D + c4);
  float p[4] = {pv.x, pv.y, pv.z, pv.w};
  bf16x4 vh, vl;
#pragma unroll
  for (int j = 0; j < 4; ++j) {
    __bf16 h = (__bf16)p[j];
    vh[j] = h;
    vl[j] = (__bf16)(p[j] - (float)h);
  }
  *(bf16x4*)(ohi + (size_t)v * 256 + 192 + c4) = vh;
  *(bf16x4*)(olo + (size_t)v * 256 + 192 + c4) = vl;
}

// ---- weights: transpose + split to bf16 hi/lo. W0 [256][256]->[n][k]; W1 [256][128]->[n][k]
__global__ __launch_bounds__(256) void wconv_kernel(
    const float* __restrict__ W0, const float* __restrict__ W1,
    __bf16* __restrict__ w0hi, __bf16* __restrict__ w0lo,
    __bf16* __restrict__ w1hi, __bf16* __restrict__ w1lo)
{
  int i = blockIdx.x * 256 + threadIdx.x;
  if (i < 65536) {
    int k = i >> 8, n = i & 255;
    float v = W0[i];
    __bf16 h = (__bf16)v;
    w0hi[n * 256 + k] = h;
    w0lo[n * 256 + k] = (__bf16)(v - (float)h);
  }
  if (i < 32768) {
    int k = i >> 7, n = i & 127;
    float v = W1[i];
    __bf16 h = (__bf16)v;
    w1hi[n * 256 + k] = h;
    w1lo[n * 256 + k] = (__bf16)(v - (float)h);
  }
}

// ---- GEMM0 (MFMA, 3-term bf16 split): A1 = bf16hi/lo(leaky(A0 @ W0 + b0)) ----
// rows [r0, r0+HALFM); A1 planes indexed by local row. 4 waves (2x2), tile 128x128, no LDS
__global__ __launch_bounds__(256) void gemm0_mfma_kernel(
    const __bf16* __restrict__ Ahi, const __bf16* __restrict__ Alo,
    const __bf16* __restrict__ Bthi, const __bf16* __restrict__ Btlo,
    const float* __restrict__ bias,
    __bf16* __restrict__ Ohi, __bf16* __restrict__ Olo, int r0)
{
  int t = threadIdx.x;
  int wid = t >> 6, lane = t & 63;
  int wrow = wid >> 1, wcol = wid & 1;
  int bm0 = r0 + blockIdx.x * 128 + wrow * 64;   // global A0 row
  int lm0 = blockIdx.x * 128 + wrow * 64;        // local A1 row
  int bn0 = blockIdx.y * 128 + wcol * 64;
  int l15 = lane & 15, lk = (lane >> 4) * 8;
  f32x4 acc[4][4];
#pragma unroll
  for (int i = 0; i < 4; ++i)
#pragma unroll
    for (int j = 0; j < 4; ++j) acc[i][j] = (f32x4){0.f, 0.f, 0.f, 0.f};

  for (int k0 = 0; k0 < 256; k0 += 32) {
    bf16x8 ah[4], al[4], bh[4], bl[4];
#pragma unroll
    for (int rt = 0; rt < 4; ++rt) {
      size_t off = (size_t)(bm0 + 16 * rt + l15) * 256 + k0 + lk;
      ah[rt] = *(const bf16x8*)(Ahi + off);
      al[rt] = *(const bf16x8*)(Alo + off);
    }
#pragma unroll
    for (int ct = 0; ct < 4; ++ct) {
      size_t off = (size_t)(bn0 + 16 * ct + l15) * 256 + k0 + lk;
      bh[ct] = *(const bf16x8*)(Bthi + off);
      bl[ct] = *(const bf16x8*)(Btlo + off);
    }
#pragma unroll
    for (int rt = 0; rt < 4; ++rt)
#pragma unroll
      for (int ct = 0; ct < 4; ++ct) {
        acc[rt][ct] = __builtin_amdgcn_mfma_f32_16x16x32_bf16(ah[rt], bh[ct], acc[rt][ct], 0, 0, 0);
        acc[rt][ct] = __builtin_amdgcn_mfma_f32_16x16x32_bf16(al[rt], bh[ct], acc[rt][ct], 0, 0, 0);
        acc[rt][ct] = __builtin_amdgcn_mfma_f32_16x16x32_bf16(ah[rt], bl[ct], acc[rt][ct], 0, 0, 0);
      }
  }
  int rbase = (lane >> 4) * 4;
#pragma unroll
  for (int ct = 0; ct < 4; ++ct) {
    int col = bn0 + 16 * ct + l15;
    float bb = bias[col];
#pragma unroll
    for (int rt = 0; rt < 4; ++rt) {
#pragma unroll
      for (int r = 0; r < 4; ++r) {
        float z = acc[rt][ct][r] + bb;
        z = (z > 0.f) ? z : 0.01f * z;
        __bf16 h = (__bf16)z;
        size_t o = (size_t)(lm0 + 16 * rt + rbase + r) * 256 + col;
        Ohi[o] = h;
        Olo[o] = (__bf16)(z - (float)h);
      }
    }
  }
}

// ---- GEMM1 (MFMA bf16, 3-term split) fused with final dot + sigmoid ----
__global__ __launch_bounds__(256) void gemm1_final_kernel(
    const __bf16* __restrict__ Ahi, const __bf16* __restrict__ Alo,
    const __bf16* __restrict__ Bthi, const __bf16* __restrict__ Btlo,
    const float* __restrict__ bias, const float* __restrict__ Wf,
    const float* __restrict__ fbias, float* __restrict__ out, int r0)
{
  __shared__ float part[2][128];
  int t = threadIdx.x;
  int wid = t >> 6, lane = t & 63;
  int wrow = wid >> 1, wcol = wid & 1;
  int lm0 = blockIdx.x * 128 + wrow * 64;   // local A1 row
  int cn0 = wcol * 64;
  int l15 = lane & 15, lk = (lane >> 4) * 8;
  f32x4 acc[4][4];
#pragma unroll
  for (int i = 0; i < 4; ++i)
#pragma unroll
    for (int j = 0; j < 4; ++j) acc[i][j] = (f32x4){0.f, 0.f, 0.f, 0.f};

  for (int k0 = 0; k0 < 256; k0 += 32) {
    bf16x8 ah[4], al[4], bh[4], bl[4];
#pragma unroll
    for (int rt = 0; rt < 4; ++rt) {
      size_t off = (size_t)(lm0 + 16 * rt + l15) * 256 + k0 + lk;
      ah[rt] = *(const bf16x8*)(Ahi + off);
      al[rt] = *(const bf16x8*)(Alo + off);
    }
#pragma unroll
    for (int ct = 0; ct < 4; ++ct) {
      size_t off = (size_t)(cn0 + 16 * ct + l15) * 256 + k0 + lk;
      bh[ct] = *(const bf16x8*)(Bthi + off);
      bl[ct] = *(const bf16x8*)(Btlo + off);
    }
#pragma unroll
    for (int rt = 0; rt < 4; ++rt)
#pragma unroll
      for (int ct = 0; ct < 4; ++ct) {
        acc[rt][ct] = __builtin_amdgcn_mfma_f32_16x16x32_bf16(ah[rt], bh[ct], acc[rt][ct], 0, 0, 0);
        acc[rt][ct] = __builtin_amdgcn_mfma_f32_16x16x32_bf16(al[rt], bh[ct], acc[rt][ct], 0, 0, 0);
        acc[rt][ct] = __builtin_amdgcn_mfma_f32_16x16x32_bf16(ah[rt], bl[ct], acc[rt][ct], 0, 0, 0);
      }
  }
  int rbase = (lane >> 4) * 4;
#pragma unroll
  for (int rt = 0; rt < 4; ++rt) {
#pragma unroll
    for (int r = 0; r < 4; ++r) {
      float p = 0.f;
#pragma unroll
      for (int ct = 0; ct < 4; ++ct) {
        int col = cn0 + 16 * ct + l15;
        float z = acc[rt][ct][r] + bias[col];
        z = (z > 0.f) ? z : 0.01f * z;
        p += z * Wf[col];
      }
      p += __shfl_xor(p, 1);
      p += __shfl_xor(p, 2);
      p += __shfl_xor(p, 4);
      p += __shfl_xor(p, 8);
      if (l15 == 0)
        part[wcol][wrow * 64 + 16 * rt + rbase + r] = p;
    }
  }
  __syncthreads();
  if (t < 128) {
    int row = r0 + blockIdx.x * 128 + t;
    if (row < N_NODES) {
      float z = part[0][t] + part[1][t] + fbias[0];
      out[row] = 1.0f / (1.0f + expf(-z));
    }
  }
}

extern "C" void kernel_launch(void* const* d_in, const int* in_sizes, int n_in,
                              void* d_out, int out_size, void* d_ws, size_t ws_size,
                              hipStream_t stream)
{
  const float* x     = (const float*)d_in[0];
  const int*   ei    = (const int*)d_in[1];
  const int*   batch = (const int*)d_in[2];
  const float* convW = (const float*)d_in[3];
  const float* convb = (const float*)d_in[4];
  const float* gam   = (const float*)d_in[5];
  const float* bet   = (const float*)d_in[6];
  const float* mean  = (const float*)d_in[7];
  const float* var   = (const float*)d_in[8];
  const float* eps   = (const float*)d_in[9];
  const float* W0    = (const float*)d_in[10];
  const float* b0    = (const float*)d_in[11];
  const float* W1    = (const float*)d_in[12];
  const float* b1    = (const float*)d_in[13];
  const float* Wf    = (const float*)d_in[14];
  const float* fb    = (const float*)d_in[15];
  float* out = (float*)d_out;

  // ---- workspace layout (float offsets), total 38,535,168 floats = 154.1 MB ----
  //  A0HI [0,        12812288)   bf16 [PADM][256] concat hi
  //  A0LO [12812288, 25624576)   bf16 concat lo
  //  A1HI [25624576, 32030720)   bf16 [HALFM][256] gemm0-out hi (phased)
  //  A1LO [32030720, 38436864)   bf16 gemm0-out lo (phased)
  //    overlays inside A1 span (all dead before first gemm0):
  //    AGG  25624576 (6.4e6) | DEG 32024576 | INCL 32124576 | ROWP 32224576
  //    CURS 32324608 | SRCS 32424608 (1e6) | BSUM 33424608 | HPOOL 33424672 (128000)
  //  WB   [38436864, 38535168)   w0hi,w0lo (32768 fl each), w1hi,w1lo (16384 fl each)
  float* ws = (float*)d_ws;
  __bf16* A0hi = (__bf16*)(ws);
  __bf16* A0lo = (__bf16*)(ws + 12812288);
  __bf16* A1hi = (__bf16*)(ws + 25624576);
  __bf16* A1lo = (__bf16*)(ws + 32030720);
  float* agg    = ws + 25624576;
  int* deg      = (int*)(ws + 32024576);
  int* incl     = (int*)(ws + 32124576);
  int* row_ptr  = (int*)(ws + 32224576);
  int* cursor   = (int*)(ws + 32324608);
  int* srcs     = (int*)(ws + 32424608);
  int* bsum     = (int*)(ws + 33424608);
  float* hpool  = ws + 33424672;
  __bf16* w0hi  = (__bf16*)(ws + 38436864);
  __bf16* w0lo  = (__bf16*)(ws + 38436864 + 32768);
  __bf16* w1hi  = (__bf16*)(ws + 38436864 + 65536);
  __bf16* w1lo  = (__bf16*)(ws + 38436864 + 81920);

  dim3 b256(256);

  wconv_kernel<<<256, b256, 0, stream>>>(W0, W1, w0hi, w0lo, w1hi, w1lo);

  // ---- CSR build (once) ----
  hipMemsetAsync(deg, 0, (size_t)N_NODES * sizeof(int), stream);
  deg_hist_kernel<<<(N_EDGES + 255) / 256, b256, 0, stream>>>(ei, deg);
  scan1_kernel<<<(N_NODES + 2047) / 2048, b256, 0, stream>>>(deg, incl, bsum);
  scan2_kernel<<<1, 64, 0, stream>>>(bsum, (N_NODES + 2047) / 2048);
  scan3_kernel<<<(N_NODES + 255) / 256, b256, 0, stream>>>(incl, bsum, deg, row_ptr, cursor);
  fill_csr_kernel<<<(N_EDGES + 255) / 256, b256, 0, stream>>>(ei, cursor, srcs);

  hipMemsetAsync(hpool, 0, (size_t)N_GRAPHS * D * sizeof(float), stream);

  int aggGrid = (N_NODES * 64 + 255) / 256;
  int gridX = PADM / 128;  // 782
  // layer 0: input x (f32), output cols 0..63
  csr_agg_kernel<0><<<aggGrid, b256, 0, stream>>>(x, nullptr, nullptr, 0, row_ptr, srcs, agg);
  conv_kernel<0, 0><<<gridX, b256, 0, stream>>>(
      x, nullptr, nullptr, 0, agg, convW, convb, gam, bet, mean, var, eps,
      A0hi, A0lo, 0, nullptr, nullptr);
  // layer 1: input cols 0..63, output cols 64..127
  csr_agg_kernel<1><<<aggGrid, b256, 0, stream>>>(nullptr, A0hi, A0lo, 0, row_ptr, srcs, agg);
  conv_kernel<1, 0><<<gridX, b256, 0, stream>>>(
      nullptr, A0hi, A0lo, 0, agg, convW + D * D, convb + D,
      gam + D, bet + D, mean + D, var + D, eps + 1,
      A0hi, A0lo, 64, nullptr, nullptr);
  // layer 2: input cols 64..127, output cols 128..191 + pool
  csr_agg_kernel<1><<<aggGrid, b256, 0, stream>>>(nullptr, A0hi, A0lo, 64, row_ptr, srcs, agg);
  conv_kernel<1, 1><<<gridX, b256, 0, stream>>>(
      nullptr, A0hi, A0lo, 64, agg, convW + 2 * D * D, convb + 2 * D,
      gam + 2 * D, bet + 2 * D, mean + 2 * D, var + 2 * D, eps + 2,
      A0hi, A0lo, 128, hpool, batch);

  pool_expand_kernel<<<(N_NODES * 16 + 255) / 256, b256, 0, stream>>>(hpool, batch, A0hi, A0lo);

  // ---- classifier, two row-phases sharing the half-size A1 buffer ----
  int gridH = HALFM / 128;  // 391
  for (int ph = 0; ph < 2; ++ph) {
    int r0 = ph * HALFM;
    gemm0_mfma_kernel<<<dim3(gridH, 2), b256, 0, stream>>>(
        A0hi, A0lo, w0hi, w0lo, b0, A1hi, A1lo, r0);
    gemm1_final_kernel<<<gridH, b256, 0, stream>>>(
        A1hi, A1lo, w1hi, w1lo, b1, Wf, fb, out, r0);
  }
}

// Round 5
// 588.508 us; speedup vs baseline: 1.9427x; 1.3981x over previous
//
#include <hip/hip_runtime.h>

#define N_NODES 100000
#define PADM    100096   // 782 * 128
#define HALFM   50048    // 391 * 128
#define N_EDGES 1000000
#define N_GRAPHS 2000
#define D 64

typedef __bf16    bf16x8 __attribute__((ext_vector_type(8)));
typedef __bf16    bf16x4 __attribute__((ext_vector_type(4)));
typedef float     f32x4  __attribute__((ext_vector_type(4)));

// ===================== CSR build (once, reused for 3 layers) =====================
__global__ __launch_bounds__(256) void deg_hist_kernel(
    const int* __restrict__ ei, int* __restrict__ deg)
{
  int i = blockIdx.x * blockDim.x + threadIdx.x;
  if (i < N_EDGES) atomicAdd(&deg[ei[N_EDGES + i]], 1);
}

__global__ __launch_bounds__(256) void scan1_kernel(
    const int* __restrict__ deg, int* __restrict__ incl, int* __restrict__ bsum)
{
  __shared__ int sh[256];
  int t = threadIdx.x;
  int base = blockIdx.x * 2048 + t * 8;
  int v[8];
  int run = 0;
#pragma unroll
  for (int j = 0; j < 8; ++j) {
    int idx = base + j;
    int xv = (idx < N_NODES) ? deg[idx] : 0;
    run += xv;
    v[j] = run;
  }
  sh[t] = run;
  __syncthreads();
  for (int off = 1; off < 256; off <<= 1) {
    int a = (t >= off) ? sh[t - off] : 0;
    __syncthreads();
    sh[t] += a;
    __syncthreads();
  }
  int prev = (t > 0) ? sh[t - 1] : 0;
#pragma unroll
  for (int j = 0; j < 8; ++j) {
    int idx = base + j;
    if (idx < N_NODES) incl[idx] = v[j] + prev;
  }
  if (t == 255) bsum[blockIdx.x] = sh[255];
}

__global__ void scan2_kernel(int* __restrict__ bsum, int nb)
{
  if (blockIdx.x == 0 && threadIdx.x == 0) {
    int run = 0;
    for (int i = 0; i < nb; ++i) { int xv = bsum[i]; bsum[i] = run; run += xv; }
  }
}

__global__ __launch_bounds__(256) void scan3_kernel(
    const int* __restrict__ incl, const int* __restrict__ bsum,
    const int* __restrict__ deg, int* __restrict__ row_ptr, int* __restrict__ cursor)
{
  int i = blockIdx.x * blockDim.x + threadIdx.x;
  if (i < N_NODES) {
    int val = incl[i] + bsum[i >> 11];
    row_ptr[i + 1] = val;
    cursor[i] = val - deg[i];
    if (i == 0) row_ptr[0] = 0;
  }
}

__global__ __launch_bounds__(256) void fill_csr_kernel(
    const int* __restrict__ ei, int* __restrict__ cursor, int* __restrict__ srcs)
{
  int i = blockIdx.x * blockDim.x + threadIdx.x;
  if (i < N_EDGES) {
    int s = ei[i];
    int d = ei[N_EDGES + i];
    int pos = atomicAdd(&cursor[d], 1);
    srcs[pos] = s;
  }
}

// ---- split f32 x into bf16 hi/lo planes [N][64] ----
__global__ __launch_bounds__(256) void split_x_kernel(
    const float* __restrict__ x, __bf16* __restrict__ xhi, __bf16* __restrict__ xlo)
{
  int idx = blockIdx.x * blockDim.x + threadIdx.x;
  if (idx >= N_NODES * 16) return;
  int v = idx >> 4, c4 = (idx & 15) << 2;
  float4 xv = *(const float4*)(x + (size_t)v * D + c4);
  float p[4] = {xv.x, xv.y, xv.z, xv.w};
  bf16x4 vh, vl;
#pragma unroll
  for (int j = 0; j < 4; ++j) {
    __bf16 h = (__bf16)p[j];
    vh[j] = h;
    vl[j] = (__bf16)(p[j] - (float)h);
  }
  *(bf16x4*)(xhi + (size_t)v * D + c4) = vh;
  *(bf16x4*)(xlo + (size_t)v * D + c4) = vl;
}

// ---- weights: transpose + split to bf16 hi/lo [n][k] layouts ----
__global__ __launch_bounds__(256) void wconv_kernel(
    const float* __restrict__ W0, const float* __restrict__ W1,
    const float* __restrict__ convW,
    __bf16* __restrict__ w0hi, __bf16* __restrict__ w0lo,
    __bf16* __restrict__ w1hi, __bf16* __restrict__ w1lo,
    __bf16* __restrict__ cwhi, __bf16* __restrict__ cwlo)
{
  int i = blockIdx.x * 256 + threadIdx.x;
  if (i < 65536) {
    int k = i >> 8, n = i & 255;
    float v = W0[i];
    __bf16 h = (__bf16)v;
    w0hi[n * 256 + k] = h;
    w0lo[n * 256 + k] = (__bf16)(v - (float)h);
  }
  if (i < 32768) {
    int k = i >> 7, n = i & 127;
    float v = W1[i];
    __bf16 h = (__bf16)v;
    w1hi[n * 256 + k] = h;
    w1lo[n * 256 + k] = (__bf16)(v - (float)h);
  }
  if (i < 12288) {
    int l = i >> 12, rem = i & 4095;
    int k = rem >> 6, n = rem & 63;
    float v = convW[i];
    __bf16 h = (__bf16)v;
    cwhi[l * 4096 + n * 64 + k] = h;
    cwlo[l * 4096 + n * 64 + k] = (__bf16)(v - (float)h);
  }
}

// ---- ygemm: y = A @ W  (MFMA 4-term bf16 split, f32 out, no bias) ----
// A planes at given stride (64 for xsplit, 256 for A0 concat w/ col offset)
// wave = 16 rows x 64 cols; 4 waves/block; grid = PADM/64
__global__ __launch_bounds__(256) void ygemm_kernel(
    const __bf16* __restrict__ Ahi, const __bf16* __restrict__ Alo, int astride,
    const __bf16* __restrict__ cwh, const __bf16* __restrict__ cwl,
    float* __restrict__ y)
{
  int t = threadIdx.x;
  int wid = t >> 6, lane = t & 63;
  int bm0 = blockIdx.x * 64 + wid * 16;
  int l15 = lane & 15, lk = (lane >> 4) * 8;
  f32x4 acc[4];
#pragma unroll
  for (int j = 0; j < 4; ++j) acc[j] = (f32x4){0.f, 0.f, 0.f, 0.f};

#pragma unroll
  for (int k0 = 0; k0 < 64; k0 += 32) {
    bf16x8 ah, al, bh[4], bl[4];
    {
      size_t off = (size_t)(bm0 + l15) * astride + k0 + lk;
      ah = *(const bf16x8*)(Ahi + off);
      al = *(const bf16x8*)(Alo + off);
    }
#pragma unroll
    for (int ct = 0; ct < 4; ++ct) {
      size_t off = (size_t)(16 * ct + l15) * 64 + k0 + lk;
      bh[ct] = *(const bf16x8*)(cwh + off);
      bl[ct] = *(const bf16x8*)(cwl + off);
    }
#pragma unroll
    for (int ct = 0; ct < 4; ++ct) {
      acc[ct] = __builtin_amdgcn_mfma_f32_16x16x32_bf16(ah, bh[ct], acc[ct], 0, 0, 0);
      acc[ct] = __builtin_amdgcn_mfma_f32_16x16x32_bf16(al, bh[ct], acc[ct], 0, 0, 0);
      acc[ct] = __builtin_amdgcn_mfma_f32_16x16x32_bf16(ah, bl[ct], acc[ct], 0, 0, 0);
      acc[ct] = __builtin_amdgcn_mfma_f32_16x16x32_bf16(al, bl[ct], acc[ct], 0, 0, 0);
    }
  }
  int rbase = (lane >> 4) * 4;
#pragma unroll
  for (int ct = 0; ct < 4; ++ct)
#pragma unroll
    for (int r = 0; r < 4; ++r)
      y[(size_t)(bm0 + rbase + r) * D + 16 * ct + l15] = acc[ct][r];
}

// ---- fused: pre = (1+eps)*y_i + sum_j y_j + b; BN; leaky^2; store planes; pool ----
template <int POOL>
__global__ __launch_bounds__(256) void agg_bn_kernel(
    const float* __restrict__ y,
    const int* __restrict__ row_ptr, const int* __restrict__ srcs,
    const float* __restrict__ bias,
    const float* __restrict__ gamma, const float* __restrict__ beta,
    const float* __restrict__ mean, const float* __restrict__ var,
    const float* __restrict__ epsp,
    __bf16* __restrict__ ohi, __bf16* __restrict__ olo, int oc0,
    float* __restrict__ hpool, const int* __restrict__ batch)
{
  int wid = (blockIdx.x * blockDim.x + threadIdx.x) >> 6;
  int lane = threadIdx.x & 63;
  if (wid >= N_NODES) return;
  float onepe = 1.0f + epsp[0];
  int beg = row_ptr[wid];
  int end = row_ptr[wid + 1];
  float s = onepe * y[(size_t)wid * D + lane];
  int e = beg;
  int n4 = beg + ((end - beg) & ~3);
  for (; e < n4; e += 4) {
    int s0 = srcs[e], s1 = srcs[e + 1], s2 = srcs[e + 2], s3 = srcs[e + 3];
    float a0 = y[(size_t)s0 * D + lane];
    float a1 = y[(size_t)s1 * D + lane];
    float a2 = y[(size_t)s2 * D + lane];
    float a3 = y[(size_t)s3 * D + lane];
    s += (a0 + a1) + (a2 + a3);
  }
  for (; e < end; ++e) s += y[(size_t)srcs[e] * D + lane];

  float sc = gamma[lane] * rsqrtf(var[lane] + 1e-5f);
  float z = (s + bias[lane] - mean[lane]) * sc + beta[lane];
  z = (z > 0.f) ? z : 0.01f * z;
  z = (z > 0.f) ? z : 0.01f * z;
  __bf16 h = (__bf16)z;
  size_t o = (size_t)wid * 256 + oc0 + lane;
  ohi[o] = h;
  olo[o] = (__bf16)(z - (float)h);
  if (POOL) {
    int g = batch[wid];
    unsafeAtomicAdd(&hpool[(size_t)g * D + lane], z);
  }
}

// ---- pool rows -> concat cols 192..255 (hi/lo bf16) ----
__global__ __launch_bounds__(256) void pool_expand_kernel(
    const float* __restrict__ hpool, const int* __restrict__ batch,
    __bf16* __restrict__ ohi, __bf16* __restrict__ olo)
{
  int idx = blockIdx.x * blockDim.x + threadIdx.x;
  int v = idx >> 4, c4 = (idx & 15) << 2;
  if (v >= N_NODES) return;
  int g = batch[v];
  float4 pv = *(const float4*)(hpool + (size_t)g * D + c4);
  float p[4] = {pv.x, pv.y, pv.z, pv.w};
  bf16x4 vh, vl;
#pragma unroll
  for (int j = 0; j < 4; ++j) {
    __bf16 h = (__bf16)p[j];
    vh[j] = h;
    vl[j] = (__bf16)(p[j] - (float)h);
  }
  *(bf16x4*)(ohi + (size_t)v * 256 + 192 + c4) = vh;
  *(bf16x4*)(olo + (size_t)v * 256 + 192 + c4) = vl;
}

// ---- GEMM0 (MFMA, 4-term bf16 split): A1 = bf16hi/lo(leaky(A0 @ W0 + b0)) ----
__global__ __launch_bounds__(256) void gemm0_mfma_kernel(
    const __bf16* __restrict__ Ahi, const __bf16* __restrict__ Alo,
    const __bf16* __restrict__ Bthi, const __bf16* __restrict__ Btlo,
    const float* __restrict__ bias,
    __bf16* __restrict__ Ohi, __bf16* __restrict__ Olo, int r0)
{
  int t = threadIdx.x;
  int wid = t >> 6, lane = t & 63;
  int wrow = wid >> 1, wcol = wid & 1;
  int bm0 = r0 + blockIdx.x * 128 + wrow * 64;   // global A0 row
  int lm0 = blockIdx.x * 128 + wrow * 64;        // local A1 row
  int bn0 = blockIdx.y * 128 + wcol * 64;
  int l15 = lane & 15, lk = (lane >> 4) * 8;
  f32x4 acc[4][4];
#pragma unroll
  for (int i = 0; i < 4; ++i)
#pragma unroll
    for (int j = 0; j < 4; ++j) acc[i][j] = (f32x4){0.f, 0.f, 0.f, 0.f};

  for (int k0 = 0; k0 < 256; k0 += 32) {
    bf16x8 ah[4], al[4], bh[4], bl[4];
#pragma unroll
    for (int rt = 0; rt < 4; ++rt) {
      size_t off = (size_t)(bm0 + 16 * rt + l15) * 256 + k0 + lk;
      ah[rt] = *(const bf16x8*)(Ahi + off);
      al[rt] = *(const bf16x8*)(Alo + off);
    }
#pragma unroll
    for (int ct = 0; ct < 4; ++ct) {
      size_t off = (size_t)(bn0 + 16 * ct + l15) * 256 + k0 + lk;
      bh[ct] = *(const bf16x8*)(Bthi + off);
      bl[ct] = *(const bf16x8*)(Btlo + off);
    }
#pragma unroll
    for (int rt = 0; rt < 4; ++rt)
#pragma unroll
      for (int ct = 0; ct < 4; ++ct) {
        acc[rt][ct] = __builtin_amdgcn_mfma_f32_16x16x32_bf16(ah[rt], bh[ct], acc[rt][ct], 0, 0, 0);
        acc[rt][ct] = __builtin_amdgcn_mfma_f32_16x16x32_bf16(al[rt], bh[ct], acc[rt][ct], 0, 0, 0);
        acc[rt][ct] = __builtin_amdgcn_mfma_f32_16x16x32_bf16(ah[rt], bl[ct], acc[rt][ct], 0, 0, 0);
        acc[rt][ct] = __builtin_amdgcn_mfma_f32_16x16x32_bf16(al[rt], bl[ct], acc[rt][ct], 0, 0, 0);
      }
  }
  int rbase = (lane >> 4) * 4;
#pragma unroll
  for (int ct = 0; ct < 4; ++ct) {
    int col = bn0 + 16 * ct + l15;
    float bb = bias[col];
#pragma unroll
    for (int rt = 0; rt < 4; ++rt) {
#pragma unroll
      for (int r = 0; r < 4; ++r) {
        float z = acc[rt][ct][r] + bb;
        z = (z > 0.f) ? z : 0.01f * z;
        __bf16 h = (__bf16)z;
        size_t o = (size_t)(lm0 + 16 * rt + rbase + r) * 256 + col;
        Ohi[o] = h;
        Olo[o] = (__bf16)(z - (float)h);
      }
    }
  }
}

// ---- GEMM1 (MFMA bf16, 4-term split) fused with final dot + sigmoid ----
__global__ __launch_bounds__(256) void gemm1_final_kernel(
    const __bf16* __restrict__ Ahi, const __bf16* __restrict__ Alo,
    const __bf16* __restrict__ Bthi, const __bf16* __restrict__ Btlo,
    const float* __restrict__ bias, const float* __restrict__ Wf,
    const float* __restrict__ fbias, float* __restrict__ out, int r0)
{
  __shared__ float part[2][128];
  int t = threadIdx.x;
  int wid = t >> 6, lane = t & 63;
  int wrow = wid >> 1, wcol = wid & 1;
  int lm0 = blockIdx.x * 128 + wrow * 64;   // local A1 row
  int cn0 = wcol * 64;
  int l15 = lane & 15, lk = (lane >> 4) * 8;
  f32x4 acc[4][4];
#pragma unroll
  for (int i = 0; i < 4; ++i)
#pragma unroll
    for (int j = 0; j < 4; ++j) acc[i][j] = (f32x4){0.f, 0.f, 0.f, 0.f};

  for (int k0 = 0; k0 < 256; k0 += 32) {
    bf16x8 ah[4], al[4], bh[4], bl[4];
#pragma unroll
    for (int rt = 0; rt < 4; ++rt) {
      size_t off = (size_t)(lm0 + 16 * rt + l15) * 256 + k0 + lk;
      ah[rt] = *(const bf16x8*)(Ahi + off);
      al[rt] = *(const bf16x8*)(Alo + off);
    }
#pragma unroll
    for (int ct = 0; ct < 4; ++ct) {
      size_t off = (size_t)(cn0 + 16 * ct + l15) * 256 + k0 + lk;
      bh[ct] = *(const bf16x8*)(Bthi + off);
      bl[ct] = *(const bf16x8*)(Btlo + off);
    }
#pragma unroll
    for (int rt = 0; rt < 4; ++rt)
#pragma unroll
      for (int ct = 0; ct < 4; ++ct) {
        acc[rt][ct] = __builtin_amdgcn_mfma_f32_16x16x32_bf16(ah[rt], bh[ct], acc[rt][ct], 0, 0, 0);
        acc[rt][ct] = __builtin_amdgcn_mfma_f32_16x16x32_bf16(al[rt], bh[ct], acc[rt][ct], 0, 0, 0);
        acc[rt][ct] = __builtin_amdgcn_mfma_f32_16x16x32_bf16(ah[rt], bl[ct], acc[rt][ct], 0, 0, 0);
        acc[rt][ct] = __builtin_amdgcn_mfma_f32_16x16x32_bf16(al[rt], bl[ct], acc[rt][ct], 0, 0, 0);
      }
  }
  int rbase = (lane >> 4) * 4;
#pragma unroll
  for (int rt = 0; rt < 4; ++rt) {
#pragma unroll
    for (int r = 0; r < 4; ++r) {
      float p = 0.f;
#pragma unroll
      for (int ct = 0; ct < 4; ++ct) {
        int col = cn0 + 16 * ct + l15;
        float z = acc[rt][ct][r] + bias[col];
        z = (z > 0.f) ? z : 0.01f * z;
        p += z * Wf[col];
      }
      p += __shfl_xor(p, 1);
      p += __shfl_xor(p, 2);
      p += __shfl_xor(p, 4);
      p += __shfl_xor(p, 8);
      if (l15 == 0)
        part[wcol][wrow * 64 + 16 * rt + rbase + r] = p;
    }
  }
  __syncthreads();
  if (t < 128) {
    int row = r0 + blockIdx.x * 128 + t;
    if (row < N_NODES) {
      float z = part[0][t] + part[1][t] + fbias[0];
      out[row] = 1.0f / (1.0f + expf(-z));
    }
  }
}

extern "C" void kernel_launch(void* const* d_in, const int* in_sizes, int n_in,
                              void* d_out, int out_size, void* d_ws, size_t ws_size,
                              hipStream_t stream)
{
  const float* x     = (const float*)d_in[0];
  const int*   ei    = (const int*)d_in[1];
  const int*   batch = (const int*)d_in[2];
  const float* convW = (const float*)d_in[3];
  const float* convb = (const float*)d_in[4];
  const float* gam   = (const float*)d_in[5];
  const float* bet   = (const float*)d_in[6];
  const float* mean  = (const float*)d_in[7];
  const float* var   = (const float*)d_in[8];
  const float* eps   = (const float*)d_in[9];
  const float* W0    = (const float*)d_in[10];
  const float* b0    = (const float*)d_in[11];
  const float* W1    = (const float*)d_in[12];
  const float* b1    = (const float*)d_in[13];
  const float* Wf    = (const float*)d_in[14];
  const float* fb    = (const float*)d_in[15];
  float* out = (float*)d_out;

  // ---- workspace layout (float offsets), peak ~160.3 MB (<= proven 179.7 MB) ----
  //  A0hi [0, 12812288)         bf16 [PADM][256] concat hi
  //  A0lo [12812288, 25624576)  bf16 concat lo
  //  y    [25624576, 32030720)  f32 [PADM][64]  (per-layer x@W; dead before classifier)
  //  A1hi [25624576, 32030720)  overlays y (classifier phase, y dead)
  //  A1lo [32030720, 38436864)
  //    xhi [32030720, 35230720), xlo [35230720, 38430720)  (overlay A1lo; dead after L0 ygemm)
  //  CSR/pool/weights [38436864, ~40075552)
  float* ws = (float*)d_ws;
  __bf16* A0hi = (__bf16*)(ws);
  __bf16* A0lo = (__bf16*)(ws + 12812288);
  float*  y    = ws + 25624576;
  __bf16* A1hi = (__bf16*)(ws + 25624576);
  __bf16* A1lo = (__bf16*)(ws + 32030720);
  __bf16* xhi  = (__bf16*)(ws + 32030720);
  __bf16* xlo  = (__bf16*)(ws + 35230720);
  int* deg     = (int*)(ws + 38436864);
  int* incl    = (int*)(ws + 38536864);
  int* row_ptr = (int*)(ws + 38636864);
  int* cursor  = (int*)(ws + 38736896);
  int* srcs    = (int*)(ws + 38836896);
  int* bsum    = (int*)(ws + 39836896);
  float* hpool = ws + 39836960;
  __bf16* w0hi = (__bf16*)(ws + 39964960);
  __bf16* w0lo = (__bf16*)(ws + 39997728);
  __bf16* w1hi = (__bf16*)(ws + 40030496);
  __bf16* w1lo = (__bf16*)(ws + 40046880);
  __bf16* cwhi = (__bf16*)(ws + 40063264);
  __bf16* cwlo = (__bf16*)(ws + 40069408);

  dim3 b256(256);

  wconv_kernel<<<256, b256, 0, stream>>>(W0, W1, convW, w0hi, w0lo, w1hi, w1lo, cwhi, cwlo);

  // ---- CSR build (once) ----
  hipMemsetAsync(deg, 0, (size_t)N_NODES * sizeof(int), stream);
  deg_hist_kernel<<<(N_EDGES + 255) / 256, b256, 0, stream>>>(ei, deg);
  scan1_kernel<<<(N_NODES + 2047) / 2048, b256, 0, stream>>>(deg, incl, bsum);
  scan2_kernel<<<1, 64, 0, stream>>>(bsum, (N_NODES + 2047) / 2048);
  scan3_kernel<<<(N_NODES + 255) / 256, b256, 0, stream>>>(incl, bsum, deg, row_ptr, cursor);
  fill_csr_kernel<<<(N_EDGES + 255) / 256, b256, 0, stream>>>(ei, cursor, srcs);

  hipMemsetAsync(hpool, 0, (size_t)N_GRAPHS * D * sizeof(float), stream);
  split_x_kernel<<<(N_NODES * 16 + 255) / 256, b256, 0, stream>>>(x, xhi, xlo);

  int ygrid = PADM / 64;                       // 1564
  int aggGrid = (N_NODES * 64 + 255) / 256;    // 25000

  // layer 0
  ygemm_kernel<<<ygrid, b256, 0, stream>>>(xhi, xlo, 64, cwhi, cwlo, y);
  agg_bn_kernel<0><<<aggGrid, b256, 0, stream>>>(
      y, row_ptr, srcs, convb, gam, bet, mean, var, eps, A0hi, A0lo, 0, nullptr, nullptr);
  // layer 1
  ygemm_kernel<<<ygrid, b256, 0, stream>>>(A0hi, A0lo, 256, cwhi + 4096, cwlo + 4096, y);
  agg_bn_kernel<0><<<aggGrid, b256, 0, stream>>>(
      y, row_ptr, srcs, convb + D, gam + D, bet + D, mean + D, var + D, eps + 1,
      A0hi, A0lo, 64, nullptr, nullptr);
  // layer 2 (+pool)
  ygemm_kernel<<<ygrid, b256, 0, stream>>>(A0hi + 64, A0lo + 64, 256, cwhi + 8192, cwlo + 8192, y);
  agg_bn_kernel<1><<<aggGrid, b256, 0, stream>>>(
      y, row_ptr, srcs, convb + 2 * D, gam + 2 * D, bet + 2 * D, mean + 2 * D,
      var + 2 * D, eps + 2, A0hi, A0lo, 128, hpool, batch);

  pool_expand_kernel<<<(N_NODES * 16 + 255) / 256, b256, 0, stream>>>(hpool, batch, A0hi, A0lo);

  // ---- classifier, two row-phases sharing the half-size A1 buffers ----
  int gridH = HALFM / 128;  // 391
  for (int ph = 0; ph < 2; ++ph) {
    int r0 = ph * HALFM;
    gemm0_mfma_kernel<<<dim3(gridH, 2), b256, 0, stream>>>(
        A0hi, A0lo, w0hi, w0lo, b0, A1hi, A1lo, r0);
    gemm1_final_kernel<<<gridH, b256, 0, stream>>>(
        A1hi, A1lo, w1hi, w1lo, b1, Wf, fb, out, r0);
  }
}

// Round 6
// 562.184 us; speedup vs baseline: 2.0337x; 1.0468x over previous
//
#include <hip/hip_runtime.h>

#define N_NODES 100000
#define PADM    100096   // 782 * 128
#define N_EDGES 1000000
#define N_GRAPHS 2000
#define D 64

typedef __bf16    bf16x8 __attribute__((ext_vector_type(8)));
typedef __bf16    bf16x4 __attribute__((ext_vector_type(4)));
typedef float     f32x4  __attribute__((ext_vector_type(4)));

// ===================== CSR build (once, reused for 3 layers) =====================
__global__ __launch_bounds__(256) void deg_hist_kernel(
    const int* __restrict__ ei, int* __restrict__ deg)
{
  int i = blockIdx.x * blockDim.x + threadIdx.x;
  if (i < N_EDGES) atomicAdd(&deg[ei[N_EDGES + i]], 1);
}

__global__ __launch_bounds__(256) void scan1_kernel(
    const int* __restrict__ deg, int* __restrict__ incl, int* __restrict__ bsum)
{
  __shared__ int sh[256];
  int t = threadIdx.x;
  int base = blockIdx.x * 2048 + t * 8;
  int v[8];
  int run = 0;
#pragma unroll
  for (int j = 0; j < 8; ++j) {
    int idx = base + j;
    int xv = (idx < N_NODES) ? deg[idx] : 0;
    run += xv;
    v[j] = run;
  }
  sh[t] = run;
  __syncthreads();
  for (int off = 1; off < 256; off <<= 1) {
    int a = (t >= off) ? sh[t - off] : 0;
    __syncthreads();
    sh[t] += a;
    __syncthreads();
  }
  int prev = (t > 0) ? sh[t - 1] : 0;
#pragma unroll
  for (int j = 0; j < 8; ++j) {
    int idx = base + j;
    if (idx < N_NODES) incl[idx] = v[j] + prev;
  }
  if (t == 255) bsum[blockIdx.x] = sh[255];
}

__global__ void scan2_kernel(int* __restrict__ bsum, int nb)
{
  if (blockIdx.x == 0 && threadIdx.x == 0) {
    int run = 0;
    for (int i = 0; i < nb; ++i) { int xv = bsum[i]; bsum[i] = run; run += xv; }
  }
}

__global__ __launch_bounds__(256) void scan3_kernel(
    const int* __restrict__ incl, const int* __restrict__ bsum,
    const int* __restrict__ deg, int* __restrict__ row_ptr, int* __restrict__ cursor)
{
  int i = blockIdx.x * blockDim.x + threadIdx.x;
  if (i < N_NODES) {
    int val = incl[i] + bsum[i >> 11];
    row_ptr[i + 1] = val;
    cursor[i] = val - deg[i];
    if (i == 0) row_ptr[0] = 0;
  }
}

__global__ __launch_bounds__(256) void fill_csr_kernel(
    const int* __restrict__ ei, int* __restrict__ cursor, int* __restrict__ srcs)
{
  int i = blockIdx.x * blockDim.x + threadIdx.x;
  if (i < N_EDGES) {
    int s = ei[i];
    int d = ei[N_EDGES + i];
    int pos = atomicAdd(&cursor[d], 1);
    srcs[pos] = s;
  }
}

// ---- split f32 x into bf16 hi/lo planes [N][64] ----
__global__ __launch_bounds__(256) void split_x_kernel(
    const float* __restrict__ x, __bf16* __restrict__ xhi, __bf16* __restrict__ xlo)
{
  int idx = blockIdx.x * blockDim.x + threadIdx.x;
  if (idx >= N_NODES * 16) return;
  int v = idx >> 4, c4 = (idx & 15) << 2;
  float4 xv = *(const float4*)(x + (size_t)v * D + c4);
  float p[4] = {xv.x, xv.y, xv.z, xv.w};
  bf16x4 vh, vl;
#pragma unroll
  for (int j = 0; j < 4; ++j) {
    __bf16 h = (__bf16)p[j];
    vh[j] = h;
    vl[j] = (__bf16)(p[j] - (float)h);
  }
  *(bf16x4*)(xhi + (size_t)v * D + c4) = vh;
  *(bf16x4*)(xlo + (size_t)v * D + c4) = vl;
}

// ---- weights: transpose + split to bf16 hi/lo [n][k] layouts ----
__global__ __launch_bounds__(256) void wconv_kernel(
    const float* __restrict__ W0, const float* __restrict__ W1,
    const float* __restrict__ convW,
    __bf16* __restrict__ w0hi, __bf16* __restrict__ w0lo,
    __bf16* __restrict__ w1hi, __bf16* __restrict__ w1lo,
    __bf16* __restrict__ cwhi, __bf16* __restrict__ cwlo)
{
  int i = blockIdx.x * 256 + threadIdx.x;
  if (i < 65536) {
    int k = i >> 8, n = i & 255;
    float v = W0[i];
    __bf16 h = (__bf16)v;
    w0hi[n * 256 + k] = h;
    w0lo[n * 256 + k] = (__bf16)(v - (float)h);
  }
  if (i < 32768) {
    int k = i >> 7, n = i & 127;
    float v = W1[i];
    __bf16 h = (__bf16)v;
    w1hi[n * 256 + k] = h;
    w1lo[n * 256 + k] = (__bf16)(v - (float)h);
  }
  if (i < 12288) {
    int l = i >> 12, rem = i & 4095;
    int k = rem >> 6, n = rem & 63;
    float v = convW[i];
    __bf16 h = (__bf16)v;
    cwhi[l * 4096 + n * 64 + k] = h;
    cwlo[l * 4096 + n * 64 + k] = (__bf16)(v - (float)h);
  }
}

// ---- ygemm: y = A @ W  (MFMA 4-term bf16 split, f32 out, no bias) ----
__global__ __launch_bounds__(256) void ygemm_kernel(
    const __bf16* __restrict__ Ahi, const __bf16* __restrict__ Alo, int astride,
    const __bf16* __restrict__ cwh, const __bf16* __restrict__ cwl,
    float* __restrict__ y)
{
  int t = threadIdx.x;
  int wid = t >> 6, lane = t & 63;
  int bm0 = blockIdx.x * 64 + wid * 16;
  int l15 = lane & 15, lk = (lane >> 4) * 8;
  f32x4 acc[4];
#pragma unroll
  for (int j = 0; j < 4; ++j) acc[j] = (f32x4){0.f, 0.f, 0.f, 0.f};

#pragma unroll
  for (int k0 = 0; k0 < 64; k0 += 32) {
    bf16x8 ah, al, bh[4], bl[4];
    {
      size_t off = (size_t)(bm0 + l15) * astride + k0 + lk;
      ah = *(const bf16x8*)(Ahi + off);
      al = *(const bf16x8*)(Alo + off);
    }
#pragma unroll
    for (int ct = 0; ct < 4; ++ct) {
      size_t off = (size_t)(16 * ct + l15) * 64 + k0 + lk;
      bh[ct] = *(const bf16x8*)(cwh + off);
      bl[ct] = *(const bf16x8*)(cwl + off);
    }
#pragma unroll
    for (int ct = 0; ct < 4; ++ct) {
      acc[ct] = __builtin_amdgcn_mfma_f32_16x16x32_bf16(ah, bh[ct], acc[ct], 0, 0, 0);
      acc[ct] = __builtin_amdgcn_mfma_f32_16x16x32_bf16(al, bh[ct], acc[ct], 0, 0, 0);
      acc[ct] = __builtin_amdgcn_mfma_f32_16x16x32_bf16(ah, bl[ct], acc[ct], 0, 0, 0);
      acc[ct] = __builtin_amdgcn_mfma_f32_16x16x32_bf16(al, bl[ct], acc[ct], 0, 0, 0);
    }
  }
  int rbase = (lane >> 4) * 4;
#pragma unroll
  for (int ct = 0; ct < 4; ++ct)
#pragma unroll
    for (int r = 0; r < 4; ++r)
      y[(size_t)(bm0 + rbase + r) * D + 16 * ct + l15] = acc[ct][r];
}

// ---- fused: pre = (1+eps)*y_i + sum_j y_j + b; BN; leaky^2; store planes; pool ----
template <int POOL>
__global__ __launch_bounds__(256) void agg_bn_kernel(
    const float* __restrict__ y,
    const int* __restrict__ row_ptr, const int* __restrict__ srcs,
    const float* __restrict__ bias,
    const float* __restrict__ gamma, const float* __restrict__ beta,
    const float* __restrict__ mean, const float* __restrict__ var,
    const float* __restrict__ epsp,
    __bf16* __restrict__ ohi, __bf16* __restrict__ olo, int oc0,
    float* __restrict__ hpool, const int* __restrict__ batch)
{
  int wid = (blockIdx.x * blockDim.x + threadIdx.x) >> 6;
  int lane = threadIdx.x & 63;
  if (wid >= N_NODES) return;
  float onepe = 1.0f + epsp[0];
  int beg = row_ptr[wid];
  int end = row_ptr[wid + 1];
  float s = onepe * y[(size_t)wid * D + lane];
  int e = beg;
  int n4 = beg + ((end - beg) & ~3);
  for (; e < n4; e += 4) {
    int s0 = srcs[e], s1 = srcs[e + 1], s2 = srcs[e + 2], s3 = srcs[e + 3];
    float a0 = y[(size_t)s0 * D + lane];
    float a1 = y[(size_t)s1 * D + lane];
    float a2 = y[(size_t)s2 * D + lane];
    float a3 = y[(size_t)s3 * D + lane];
    s += (a0 + a1) + (a2 + a3);
  }
  for (; e < end; ++e) s += y[(size_t)srcs[e] * D + lane];

  float sc = gamma[lane] * rsqrtf(var[lane] + 1e-5f);
  float z = (s + bias[lane] - mean[lane]) * sc + beta[lane];
  z = (z > 0.f) ? z : 0.01f * z;
  z = (z > 0.f) ? z : 0.01f * z;
  __bf16 h = (__bf16)z;
  size_t o = (size_t)wid * 256 + oc0 + lane;
  ohi[o] = h;
  olo[o] = (__bf16)(z - (float)h);
  if (POOL) {
    int g = batch[wid];
    unsafeAtomicAdd(&hpool[(size_t)g * D + lane], z);
  }
}

// ---- pool rows -> concat cols 192..255 (hi/lo bf16) ----
__global__ __launch_bounds__(256) void pool_expand_kernel(
    const float* __restrict__ hpool, const int* __restrict__ batch,
    __bf16* __restrict__ ohi, __bf16* __restrict__ olo)
{
  int idx = blockIdx.x * blockDim.x + threadIdx.x;
  int v = idx >> 4, c4 = (idx & 15) << 2;
  if (v >= N_NODES) return;
  int g = batch[v];
  float4 pv = *(const float4*)(hpool + (size_t)g * D + c4);
  float p[4] = {pv.x, pv.y, pv.z, pv.w};
  bf16x4 vh, vl;
#pragma unroll
  for (int j = 0; j < 4; ++j) {
    __bf16 h = (__bf16)p[j];
    vh[j] = h;
    vl[j] = (__bf16)(p[j] - (float)h);
  }
  *(bf16x4*)(ohi + (size_t)v * 256 + 192 + c4) = vh;
  *(bf16x4*)(olo + (size_t)v * 256 + 192 + c4) = vl;
}

// ==== fused classifier: out = sigmoid(leaky(leaky(A0@W0+b0)@W1+b1)·Wf + fb) ====
// block = 32 rows, 4 waves. Phase A: ha (32x256) -> LDS bf16 hi/lo (XOR-swizzled).
// Phase B: h2 from LDS, dot Wf, reduce, sigmoid. 3-term bf16 splits.
__global__ __launch_bounds__(256) void clf_fused_kernel(
    const __bf16* __restrict__ Ahi, const __bf16* __restrict__ Alo,
    const __bf16* __restrict__ w0h, const __bf16* __restrict__ w0l,
    const float* __restrict__ b0,
    const __bf16* __restrict__ w1h, const __bf16* __restrict__ w1l,
    const float* __restrict__ b1,
    const float* __restrict__ Wf, const float* __restrict__ fbias,
    float* __restrict__ out)
{
  __shared__ __bf16 HaS[32 * 256];
  __shared__ __bf16 LaS[32 * 256];
  int t = threadIdx.x;
  int w = t >> 6, lane = t & 63;
  int l15 = lane & 15, lk = (lane >> 4) * 8;
  int rbase = (lane >> 4) * 4;
  int bm0 = blockIdx.x * 32;

  // ---- Phase A: ha[32][256], wave w owns cols [64w, 64w+64) ----
  f32x4 acc[2][4];
#pragma unroll
  for (int i = 0; i < 2; ++i)
#pragma unroll
    for (int j = 0; j < 4; ++j) acc[i][j] = (f32x4){0.f, 0.f, 0.f, 0.f};

  for (int k0 = 0; k0 < 256; k0 += 32) {
    bf16x8 ah[2], al[2], bh[4], bl[4];
#pragma unroll
    for (int rt = 0; rt < 2; ++rt) {
      size_t off = (size_t)(bm0 + 16 * rt + l15) * 256 + k0 + lk;
      ah[rt] = *(const bf16x8*)(Ahi + off);
      al[rt] = *(const bf16x8*)(Alo + off);
    }
#pragma unroll
    for (int ct = 0; ct < 4; ++ct) {
      size_t off = (size_t)(64 * w + 16 * ct + l15) * 256 + k0 + lk;
      bh[ct] = *(const bf16x8*)(w0h + off);
      bl[ct] = *(const bf16x8*)(w0l + off);
    }
#pragma unroll
    for (int rt = 0; rt < 2; ++rt)
#pragma unroll
      for (int ct = 0; ct < 4; ++ct) {
        acc[rt][ct] = __builtin_amdgcn_mfma_f32_16x16x32_bf16(ah[rt], bh[ct], acc[rt][ct], 0, 0, 0);
        acc[rt][ct] = __builtin_amdgcn_mfma_f32_16x16x32_bf16(al[rt], bh[ct], acc[rt][ct], 0, 0, 0);
        acc[rt][ct] = __builtin_amdgcn_mfma_f32_16x16x32_bf16(ah[rt], bl[ct], acc[rt][ct], 0, 0, 0);
      }
  }
  // epilogue A: bias + leaky, split hi/lo, swizzled LDS store
#pragma unroll
  for (int rt = 0; rt < 2; ++rt)
#pragma unroll
    for (int ct = 0; ct < 4; ++ct) {
      int col = 64 * w + 16 * ct + l15;
      float bb = b0[col];
#pragma unroll
      for (int r = 0; r < 4; ++r) {
        int row = 16 * rt + rbase + r;
        float z = acc[rt][ct][r] + bb;
        z = (z > 0.f) ? z : 0.01f * z;
        __bf16 h = (__bf16)z;
        unsigned bo = (unsigned)(row * 512 + col * 2) ^ ((row & 7) << 4);
        *(__bf16*)((char*)HaS + bo) = h;
        *(__bf16*)((char*)LaS + bo) = (__bf16)(z - (float)h);
      }
    }
  __syncthreads();

  // ---- Phase B: h2[32][128], wave w owns cols [32w, 32w+32) ----
  f32x4 acc2[2][2];
#pragma unroll
  for (int i = 0; i < 2; ++i)
#pragma unroll
    for (int j = 0; j < 2; ++j) acc2[i][j] = (f32x4){0.f, 0.f, 0.f, 0.f};

  for (int k0 = 0; k0 < 256; k0 += 32) {
    bf16x8 ah2[2], al2[2], b2h[2], b2l[2];
#pragma unroll
    for (int rt = 0; rt < 2; ++rt) {
      int row = 16 * rt + l15;
      unsigned bo = (unsigned)(row * 512 + (k0 + lk) * 2) ^ ((row & 7) << 4);
      ah2[rt] = *(const bf16x8*)((char*)HaS + bo);
      al2[rt] = *(const bf16x8*)((char*)LaS + bo);
    }
#pragma unroll
    for (int ct = 0; ct < 2; ++ct) {
      size_t off = (size_t)(32 * w + 16 * ct + l15) * 256 + k0 + lk;
      b2h[ct] = *(const bf16x8*)(w1h + off);
      b2l[ct] = *(const bf16x8*)(w1l + off);
    }
#pragma unroll
    for (int rt = 0; rt < 2; ++rt)
#pragma unroll
      for (int ct = 0; ct < 2; ++ct) {
        acc2[rt][ct] = __builtin_amdgcn_mfma_f32_16x16x32_bf16(ah2[rt], b2h[ct], acc2[rt][ct], 0, 0, 0);
        acc2[rt][ct] = __builtin_amdgcn_mfma_f32_16x16x32_bf16(al2[rt], b2h[ct], acc2[rt][ct], 0, 0, 0);
        acc2[rt][ct] = __builtin_amdgcn_mfma_f32_16x16x32_bf16(ah2[rt], b2l[ct], acc2[rt][ct], 0, 0, 0);
      }
  }
  __syncthreads();  // all LDS ha reads done; safe to alias part onto HaS

  float* partS = (float*)HaS;
#pragma unroll
  for (int rt = 0; rt < 2; ++rt) {
#pragma unroll
    for (int r = 0; r < 4; ++r) {
      int row = 16 * rt + rbase + r;
      float p = 0.f;
#pragma unroll
      for (int ct = 0; ct < 2; ++ct) {
        int c = 32 * w + 16 * ct + l15;
        float z = acc2[rt][ct][r] + b1[c];
        z = (z > 0.f) ? z : 0.01f * z;
        p += z * Wf[c];
      }
      p += __shfl_xor(p, 1);
      p += __shfl_xor(p, 2);
      p += __shfl_xor(p, 4);
      p += __shfl_xor(p, 8);
      if (l15 == 0) partS[w * 32 + row] = p;
    }
  }
  __syncthreads();
  if (t < 32) {
    int g = bm0 + t;
    if (g < N_NODES) {
      float z = partS[t] + partS[32 + t] + partS[64 + t] + partS[96 + t] + fbias[0];
      out[g] = 1.0f / (1.0f + expf(-z));
    }
  }
}

extern "C" void kernel_launch(void* const* d_in, const int* in_sizes, int n_in,
                              void* d_out, int out_size, void* d_ws, size_t ws_size,
                              hipStream_t stream)
{
  const float* x     = (const float*)d_in[0];
  const int*   ei    = (const int*)d_in[1];
  const int*   batch = (const int*)d_in[2];
  const float* convW = (const float*)d_in[3];
  const float* convb = (const float*)d_in[4];
  const float* gam   = (const float*)d_in[5];
  const float* bet   = (const float*)d_in[6];
  const float* mean  = (const float*)d_in[7];
  const float* var   = (const float*)d_in[8];
  const float* eps   = (const float*)d_in[9];
  const float* W0    = (const float*)d_in[10];
  const float* b0    = (const float*)d_in[11];
  const float* W1    = (const float*)d_in[12];
  const float* b1    = (const float*)d_in[13];
  const float* Wf    = (const float*)d_in[14];
  const float* fb    = (const float*)d_in[15];
  float* out = (float*)d_out;

  // ---- workspace layout (float offsets), peak ~160.3 MB ----
  //  A0hi [0, 12812288)         bf16 [PADM][256] concat hi
  //  A0lo [12812288, 25624576)  bf16 concat lo
  //  y    [25624576, 32030720)  f32 [PADM][64]
  //  xhi  [32030720, 35230720), xlo [35230720, 38430720)
  //  CSR/pool/weights [38436864, ~40075552)
  float* ws = (float*)d_ws;
  __bf16* A0hi = (__bf16*)(ws);
  __bf16* A0lo = (__bf16*)(ws + 12812288);
  float*  y    = ws + 25624576;
  __bf16* xhi  = (__bf16*)(ws + 32030720);
  __bf16* xlo  = (__bf16*)(ws + 35230720);
  int* deg     = (int*)(ws + 38436864);
  int* incl    = (int*)(ws + 38536864);
  int* row_ptr = (int*)(ws + 38636864);
  int* cursor  = (int*)(ws + 38736896);
  int* srcs    = (int*)(ws + 38836896);
  int* bsum    = (int*)(ws + 39836896);
  float* hpool = ws + 39836960;
  __bf16* w0hi = (__bf16*)(ws + 39964960);
  __bf16* w0lo = (__bf16*)(ws + 39997728);
  __bf16* w1hi = (__bf16*)(ws + 40030496);
  __bf16* w1lo = (__bf16*)(ws + 40046880);
  __bf16* cwhi = (__bf16*)(ws + 40063264);
  __bf16* cwlo = (__bf16*)(ws + 40069408);

  dim3 b256(256);

  wconv_kernel<<<256, b256, 0, stream>>>(W0, W1, convW, w0hi, w0lo, w1hi, w1lo, cwhi, cwlo);

  // ---- CSR build (once) ----
  hipMemsetAsync(deg, 0, (size_t)N_NODES * sizeof(int), stream);
  deg_hist_kernel<<<(N_EDGES + 255) / 256, b256, 0, stream>>>(ei, deg);
  scan1_kernel<<<(N_NODES + 2047) / 2048, b256, 0, stream>>>(deg, incl, bsum);
  scan2_kernel<<<1, 64, 0, stream>>>(bsum, (N_NODES + 2047) / 2048);
  scan3_kernel<<<(N_NODES + 255) / 256, b256, 0, stream>>>(incl, bsum, deg, row_ptr, cursor);
  fill_csr_kernel<<<(N_EDGES + 255) / 256, b256, 0, stream>>>(ei, cursor, srcs);

  hipMemsetAsync(hpool, 0, (size_t)N_GRAPHS * D * sizeof(float), stream);
  split_x_kernel<<<(N_NODES * 16 + 255) / 256, b256, 0, stream>>>(x, xhi, xlo);

  int ygrid = PADM / 64;                       // 1564
  int aggGrid = (N_NODES * 64 + 255) / 256;    // 25000

  // layer 0
  ygemm_kernel<<<ygrid, b256, 0, stream>>>(xhi, xlo, 64, cwhi, cwlo, y);
  agg_bn_kernel<0><<<aggGrid, b256, 0, stream>>>(
      y, row_ptr, srcs, convb, gam, bet, mean, var, eps, A0hi, A0lo, 0, nullptr, nullptr);
  // layer 1
  ygemm_kernel<<<ygrid, b256, 0, stream>>>(A0hi, A0lo, 256, cwhi + 4096, cwlo + 4096, y);
  agg_bn_kernel<0><<<aggGrid, b256, 0, stream>>>(
      y, row_ptr, srcs, convb + D, gam + D, bet + D, mean + D, var + D, eps + 1,
      A0hi, A0lo, 64, nullptr, nullptr);
  // layer 2 (+pool)
  ygemm_kernel<<<ygrid, b256, 0, stream>>>(A0hi + 64, A0lo + 64, 256, cwhi + 8192, cwlo + 8192, y);
  agg_bn_kernel<1><<<aggGrid, b256, 0, stream>>>(
      y, row_ptr, srcs, convb + 2 * D, gam + 2 * D, bet + 2 * D, mean + 2 * D,
      var + 2 * D, eps + 2, A0hi, A0lo, 128, hpool, batch);

  pool_expand_kernel<<<(N_NODES * 16 + 255) / 256, b256, 0, stream>>>(hpool, batch, A0hi, A0lo);

  // ---- fused classifier (single launch, no A1 round-trip) ----
  clf_fused_kernel<<<PADM / 32, b256, 0, stream>>>(
      A0hi, A0lo, w0hi, w0lo, b0, w1hi, w1lo, b1, Wf, fb, out);
}